// Round 1
// baseline (3187.450 us; speedup 1.0000x reference)
//
#include <hip/hip_runtime.h>
#include <math.h>

#define CIN 3
#define HIN 256
#define WIN 256
#define ND 256
#define NK 512
#define HP 128
#define WP 128
#define NPOS (HP*WP)
#define NB 16
#define QOUT ((size_t)NB*(size_t)ND*(size_t)NPOS)      // 67108864
#define IDXOUT ((size_t)NB*(size_t)NPOS)               // 262144
#define LOSS_OFF (QOUT + IDXOUT)
#define CHUNK 64
#define NCHUNK (NK/CHUNK)
#define DT 32
#define NDT (ND/DT)
#define REFINE_EPS 0.02f
#define MAX_REFINE 16
#define BN_EPSF 1e-5f

struct SMem {
    float xe[64][ND];          // 64 KiB, XOR-swizzled in 4-float groups
    float cbt[CHUNK][DT];      // 8 KiB, XOR-swizzled
    float in[CIN][18][20];     // 4.3 KiB input halo (persists for refinement)
    int   bestidx[64];
    int   refine_pos[MAX_REFINE];
    int   refine_c1[MAX_REFINE];
    int   refine_c2[MAX_REFINE];
    int   refine_count;
    double red[16];
    float losspart[4];
};

__device__ __forceinline__ void top2_insert(float s, int c,
                                            float& b1, int& i1,
                                            float& b2, int& i2) {
    bool better1 = (s < b1) || (s == b1 && c < i1);
    if (better1) { b2 = b1; i2 = i1; b1 = s; i1 = c; }
    else {
        bool better2 = (s < b2) || (s == b2 && c < i2);
        if (better2) { b2 = s; i2 = c; }
    }
}

__global__ void prep_kernel(const float* __restrict__ cb, float* __restrict__ c2,
                            float* __restrict__ loss_out) {
    int c = blockIdx.x * blockDim.x + threadIdx.x;
    if (c < NK) {
        const float4* row = reinterpret_cast<const float4*>(cb + (size_t)c * ND);
        float s = 0.f;
        #pragma unroll 8
        for (int i = 0; i < ND / 4; i++) {
            float4 v = row[i];
            s = fmaf(v.x, v.x, s); s = fmaf(v.y, v.y, s);
            s = fmaf(v.z, v.z, s); s = fmaf(v.w, v.w, s);
        }
        c2[c] = s;
    }
    if (blockIdx.x == 0 && threadIdx.x == 0) *loss_out = 0.f;
}

__global__ __launch_bounds__(256, 2)
void vqvae_kernel(const float* __restrict__ x, const float* __restrict__ conv_w,
                  const float* __restrict__ conv_b, const float* __restrict__ gamma,
                  const float* __restrict__ beta, const float* __restrict__ mean,
                  const float* __restrict__ var, const float* __restrict__ cb,
                  const float* __restrict__ c2w, float* __restrict__ out) {
    __shared__ SMem sm;
    const int t = threadIdx.x;
    const int blk = blockIdx.x;
    const int b = blk >> 8;                 // 256 tiles per image
    const int tile = blk & 255;
    const int ty0 = (tile >> 4) * 8;        // pooled-row origin
    const int tx0 = (tile & 15) * 8;

    // ---------------- stage input halo (18x18x3, zero-padded) ----------------
    {
        const int iy0 = ty0 * 2 - 1;
        const int ix0 = tx0 * 2 - 1;
        for (int e = t; e < CIN * 18 * 18; e += 256) {
            int c = e / 324;
            int rem = e - c * 324;
            int r = rem / 18;
            int cc = rem - r * 18;
            int iy = iy0 + r, ix = ix0 + cc;
            float v = 0.f;
            if (iy >= 0 && iy < HIN && ix >= 0 && ix < WIN)
                v = x[(((size_t)b * CIN + c) * HIN + iy) * WIN + ix];
            sm.in[c][r][cc] = v;
        }
        if (t == 0) sm.refine_count = 0;
    }
    __syncthreads();

    // ------------- conv3x3 + bias + maxpool2 + BN + exact GELU --------------
    // thread t owns output channel d = t for all 64 pooled positions
    {
        const int d = t;
        float w[27];
        #pragma unroll
        for (int q = 0; q < 27; q++) w[q] = conv_w[d * 27 + q];
        const float bias = conv_b[d];
        const float inv = gamma[d] / sqrtf(var[d] + BN_EPSF);
        const float mu = mean[d], bet = beta[d];
        for (int pos = 0; pos < 64; pos++) {
            const int py = pos >> 3, px = pos & 7;
            const int r0 = py * 2, c0 = px * 2;
            float s00 = bias, s01 = bias, s10 = bias, s11 = bias;
            #pragma unroll
            for (int c = 0; c < 3; c++) {
                #pragma unroll
                for (int r = 0; r < 4; r++) {
                    float v0 = sm.in[c][r0 + r][c0 + 0];
                    float v1 = sm.in[c][r0 + r][c0 + 1];
                    float v2 = sm.in[c][r0 + r][c0 + 2];
                    float v3 = sm.in[c][r0 + r][c0 + 3];
                    if (r <= 2) {
                        s00 = fmaf(w[c*9 + r*3 + 0], v0, s00);
                        s00 = fmaf(w[c*9 + r*3 + 1], v1, s00);
                        s00 = fmaf(w[c*9 + r*3 + 2], v2, s00);
                        s01 = fmaf(w[c*9 + r*3 + 0], v1, s01);
                        s01 = fmaf(w[c*9 + r*3 + 1], v2, s01);
                        s01 = fmaf(w[c*9 + r*3 + 2], v3, s01);
                    }
                    if (r >= 1) {
                        s10 = fmaf(w[c*9 + (r-1)*3 + 0], v0, s10);
                        s10 = fmaf(w[c*9 + (r-1)*3 + 1], v1, s10);
                        s10 = fmaf(w[c*9 + (r-1)*3 + 2], v2, s10);
                        s11 = fmaf(w[c*9 + (r-1)*3 + 0], v1, s11);
                        s11 = fmaf(w[c*9 + (r-1)*3 + 1], v2, s11);
                        s11 = fmaf(w[c*9 + (r-1)*3 + 2], v3, s11);
                    }
                }
            }
            float m = fmaxf(fmaxf(s00, s01), fmaxf(s10, s11));
            float bn = (m - mu) * inv + bet;
            float g = 0.5f * bn * (1.0f + erff(bn * 0.7071067811865475f));
            int gs = (d >> 2) ^ (pos & 7);
            sm.xe[pos][gs * 4 + (d & 3)] = g;
        }
    }
    __syncthreads();

    // ----------------- VQ: scores = 0.5*|c|^2 - x.c, top-2 ------------------
    const int ty = t >> 4, tx = t & 15;   // rows = ty+16i, cols = tx+16j
    float best1[4], best2[4];
    int bi1[4], bi2[4];
    #pragma unroll
    for (int i = 0; i < 4; i++) { best1[i] = best2[i] = INFINITY; bi1[i] = bi2[i] = 0x7fffffff; }

    for (int ch = 0; ch < NCHUNK; ch++) {
        float acc[4][4];
        #pragma unroll
        for (int i = 0; i < 4; i++)
            #pragma unroll
            for (int j = 0; j < 4; j++) acc[i][j] = 0.f;

        for (int dt = 0; dt < NDT; dt++) {
            __syncthreads();  // protect previous tile reads
            for (int e = t; e < CHUNK * DT; e += 256) {
                int cc = e >> 5;
                int dd = e & 31;
                float v = cb[((size_t)(ch * CHUNK + cc)) * ND + dt * DT + dd];
                int gg = (dd >> 2) ^ (cc & 7);
                sm.cbt[cc][gg * 4 + (dd & 3)] = v;
            }
            __syncthreads();
            #pragma unroll
            for (int g = 0; g < DT / 4; g++) {
                const int gfull = dt * (DT / 4) + g;
                float4 a[4];
                #pragma unroll
                for (int i = 0; i < 4; i++) {
                    int row = ty + 16 * i;
                    a[i] = *reinterpret_cast<const float4*>(
                        &sm.xe[row][((gfull ^ (row & 7)) << 2)]);
                }
                #pragma unroll
                for (int j = 0; j < 4; j++) {
                    int cc = tx + 16 * j;
                    float4 bv = *reinterpret_cast<const float4*>(
                        &sm.cbt[cc][((g ^ (cc & 7)) << 2)]);
                    #pragma unroll
                    for (int i = 0; i < 4; i++) {
                        acc[i][j] = fmaf(a[i].x, bv.x, acc[i][j]);
                        acc[i][j] = fmaf(a[i].y, bv.y, acc[i][j]);
                        acc[i][j] = fmaf(a[i].z, bv.z, acc[i][j]);
                        acc[i][j] = fmaf(a[i].w, bv.w, acc[i][j]);
                    }
                }
            }
        }
        #pragma unroll
        for (int j = 0; j < 4; j++) {
            int code = ch * CHUNK + tx + 16 * j;
            float half_c2 = 0.5f * c2w[code];
            #pragma unroll
            for (int i = 0; i < 4; i++) {
                float s = half_c2 - acc[i][j];
                top2_insert(s, code, best1[i], bi1[i], best2[i], bi2[i]);
            }
        }
    }

    // cross-tx top-2 merge (lanes differ only in low 4 bits -> in-wave shfl)
    #pragma unroll
    for (int i = 0; i < 4; i++) {
        float b1 = best1[i], b2 = best2[i];
        int i1 = bi1[i], i2 = bi2[i];
        for (int off = 1; off < 16; off <<= 1) {
            float o1 = __shfl_xor(b1, off, 64);
            int   oi1 = __shfl_xor(i1, off, 64);
            float o2 = __shfl_xor(b2, off, 64);
            int   oi2 = __shfl_xor(i2, off, 64);
            top2_insert(o1, oi1, b1, i1, b2, i2);
            top2_insert(o2, oi2, b1, i1, b2, i2);
        }
        best1[i] = b1; best2[i] = b2; bi1[i] = i1; bi2[i] = i2;
    }
    if (tx == 0) {
        #pragma unroll
        for (int i = 0; i < 4; i++) {
            int pos = ty + 16 * i;
            sm.bestidx[pos] = bi1[i];
            if (best2[i] - best1[i] < REFINE_EPS) {
                int slot = atomicAdd(&sm.refine_count, 1);
                if (slot < MAX_REFINE) {
                    sm.refine_pos[slot] = pos;
                    sm.refine_c1[slot] = bi1[i];
                    sm.refine_c2[slot] = bi2[i];
                }
            }
        }
    }
    __syncthreads();

    // --------- rare double-precision refinement for near-tie rows -----------
    {
        int nref = sm.refine_count;
        if (nref > MAX_REFINE) nref = MAX_REFINE;
        for (int rr = 0; rr < nref; rr++) {
            const int pos = sm.refine_pos[rr];
            const int c1 = sm.refine_c1[rr];
            const int c2r = sm.refine_c2[rr];
            const int d = t;
            const int py = pos >> 3, px = pos & 7;
            const int r0 = py * 2, c0 = px * 2;
            double s00, s01, s10, s11;
            s00 = s01 = s10 = s11 = (double)conv_b[d];
            for (int c = 0; c < 3; c++) {
                for (int r = 0; r < 4; r++) {
                    double v0 = (double)sm.in[c][r0 + r][c0 + 0];
                    double v1 = (double)sm.in[c][r0 + r][c0 + 1];
                    double v2 = (double)sm.in[c][r0 + r][c0 + 2];
                    double v3 = (double)sm.in[c][r0 + r][c0 + 3];
                    if (r <= 2) {
                        double w0 = (double)conv_w[d*27 + c*9 + r*3 + 0];
                        double w1 = (double)conv_w[d*27 + c*9 + r*3 + 1];
                        double w2 = (double)conv_w[d*27 + c*9 + r*3 + 2];
                        s00 = fma(w0, v0, s00); s00 = fma(w1, v1, s00); s00 = fma(w2, v2, s00);
                        s01 = fma(w0, v1, s01); s01 = fma(w1, v2, s01); s01 = fma(w2, v3, s01);
                    }
                    if (r >= 1) {
                        double w0 = (double)conv_w[d*27 + c*9 + (r-1)*3 + 0];
                        double w1 = (double)conv_w[d*27 + c*9 + (r-1)*3 + 1];
                        double w2 = (double)conv_w[d*27 + c*9 + (r-1)*3 + 2];
                        s10 = fma(w0, v0, s10); s10 = fma(w1, v1, s10); s10 = fma(w2, v2, s10);
                        s11 = fma(w0, v1, s11); s11 = fma(w1, v2, s11); s11 = fma(w2, v3, s11);
                    }
                }
            }
            double m = fmax(fmax(s00, s01), fmax(s10, s11));
            double bn = (m - (double)mean[d]) * ((double)gamma[d] /
                        sqrt((double)var[d] + 1e-5)) + (double)beta[d];
            double xd = 0.5 * bn * (1.0 + erf(bn * 0.70710678118654752440));
            double cv1 = (double)cb[(size_t)c1 * ND + d];
            double cv2 = (double)cb[(size_t)c2r * ND + d];
            double p1 = xd * cv1, p2 = xd * cv2;
            double q1 = cv1 * cv1, q2 = cv2 * cv2;
            for (int off = 32; off; off >>= 1) {
                p1 += __shfl_xor(p1, off, 64);
                p2 += __shfl_xor(p2, off, 64);
                q1 += __shfl_xor(q1, off, 64);
                q2 += __shfl_xor(q2, off, 64);
            }
            int wav = t >> 6;
            if ((t & 63) == 0) {
                sm.red[wav * 4 + 0] = p1; sm.red[wav * 4 + 1] = p2;
                sm.red[wav * 4 + 2] = q1; sm.red[wav * 4 + 3] = q2;
            }
            __syncthreads();
            if (t == 0) {
                double dot1 = sm.red[0] + sm.red[4] + sm.red[8] + sm.red[12];
                double dot2 = sm.red[1] + sm.red[5] + sm.red[9] + sm.red[13];
                double cs1 = sm.red[2] + sm.red[6] + sm.red[10] + sm.red[14];
                double cs2 = sm.red[3] + sm.red[7] + sm.red[11] + sm.red[15];
                double sc1 = 0.5 * cs1 - dot1;
                double sc2 = 0.5 * cs2 - dot2;
                bool take1 = (sc1 < sc2) || (sc1 == sc2 && c1 < c2r);
                sm.bestidx[pos] = take1 ? c1 : c2r;
            }
            __syncthreads();
        }
    }

    // --------------- write quant (NCHW), indices, commit loss ---------------
    {
        const int pos = t & 63;
        const int wv = t >> 6;               // d = wv + 4k
        const int py = pos >> 3, px = pos & 7;
        const int h = ty0 + py, wc = tx0 + px;
        const int hw = h * WP + wc;
        const int code = sm.bestidx[pos];
        if (wv == 0)
            out[QOUT + (size_t)b * NPOS + hw] = (float)code;
        const float* crow = cb + (size_t)code * ND;
        float* qbase = out + (size_t)b * ND * NPOS + hw;
        float lsum = 0.f;
        #pragma unroll
        for (int k = 0; k < 64; k++) {
            int d = wv + 4 * k;
            float cv = crow[d];
            int gs = (d >> 2) ^ (pos & 7);
            float xv = sm.xe[pos][gs * 4 + (d & 3)];
            float diff = xv - cv;
            lsum = fmaf(diff, diff, lsum);
            qbase[(size_t)d * NPOS] = cv;
        }
        #pragma unroll
        for (int off = 32; off; off >>= 1) lsum += __shfl_xor(lsum, off, 64);
        if ((t & 63) == 0) sm.losspart[t >> 6] = lsum;
        __syncthreads();
        if (t == 0) {
            float tot = sm.losspart[0] + sm.losspart[1] + sm.losspart[2] + sm.losspart[3];
            atomicAdd(out + LOSS_OFF, tot * (1.0f / 67108864.0f));
        }
    }
}

extern "C" void kernel_launch(void* const* d_in, const int* in_sizes, int n_in,
                              void* d_out, int out_size, void* d_ws, size_t ws_size,
                              hipStream_t stream) {
    const float* x      = (const float*)d_in[0];
    const float* conv_w = (const float*)d_in[1];
    const float* conv_b = (const float*)d_in[2];
    const float* gammap = (const float*)d_in[3];
    const float* betap  = (const float*)d_in[4];
    const float* meanp  = (const float*)d_in[5];
    const float* varp   = (const float*)d_in[6];
    const float* cb     = (const float*)d_in[7];
    float* out = (float*)d_out;
    float* c2w = (float*)d_ws;     // 512 floats

    prep_kernel<<<2, 256, 0, stream>>>(cb, c2w, out + LOSS_OFF);
    vqvae_kernel<<<NB * 256, 256, 0, stream>>>(x, conv_w, conv_b, gammap, betap,
                                               meanp, varp, cb, c2w, out);
}

// Round 2
// 990.062 us; speedup vs baseline: 3.2194x; 3.2194x over previous
//
#include <hip/hip_runtime.h>
#include <math.h>

#define CIN 3
#define HIN 256
#define WIN 256
#define ND 256
#define NK 512
#define HP 128
#define WP 128
#define NPOS (HP*WP)
#define NB 16
#define QOUT ((size_t)NB*(size_t)ND*(size_t)NPOS)      // 67108864
#define IDXOUT ((size_t)NB*(size_t)NPOS)               // 262144
#define LOSS_OFF (QOUT + IDXOUT)
#define REFINE_EPS 0.02f
#define MAX_REFINE 16
#define BN_EPSF 1e-5f

// tile: 4 pooled rows x 16 pooled cols = 64 positions per block
#define TR 4
#define TC 16
#define HALO_R 10
#define HALO_C 34

typedef __bf16 bf16x8 __attribute__((ext_vector_type(8)));
typedef float  f32x4  __attribute__((ext_vector_type(4)));

// ws layout (bytes): [0,2048) float c2[512]; [2048, 264192) bf16 hi frags
// (256 frags x 64 lanes x 8 bf16); [264192, 526336) bf16 lo frags.
#define WS_C2_FLOATS 512
#define WS_HI_SHORT_OFF 1024
#define WS_LO_SHORT_OFF (1024 + 131072)

struct SMem {
    alignas(16) unsigned short xhi[64 * ND];   // 32 KiB, 16B-group XOR swizzle
    alignas(16) unsigned short xlo[64 * ND];   // 32 KiB
    float halo[CIN][HALO_R][HALO_C];           // 4.1 KiB (persists for refine)
    float ms1[4 * 64];                         // per-wave top1 score
    float ms2[4 * 64];
    int   mi1[4 * 64];
    int   mi2[4 * 64];
    int   bestidx[64];
    int   refine_pos[MAX_REFINE];
    int   refine_c1[MAX_REFINE];
    int   refine_c2[MAX_REFINE];
    int   refine_count;
    float sqbuf[4];
    float s1tot;
    double red[16];
};

__device__ __forceinline__ void top2_insert(float s, int c,
                                            float& b1, int& i1,
                                            float& b2, int& i2) {
    if (c == i1) {                      // dedupe: same candidate as current best
        if (s < b1) b1 = s;
        return;
    }
    bool better1 = (s < b1) || (s == b1 && c < i1);
    if (better1) { b2 = b1; i2 = i1; b1 = s; i1 = c; }
    else {
        bool better2 = (s < b2) || (s == b2 && c < i2);
        if (better2) { b2 = s; i2 = c; }
    }
}

__global__ void prep_kernel(const float* __restrict__ cb, float* __restrict__ c2,
                            unsigned short* __restrict__ wsh,
                            unsigned short* __restrict__ wsl,
                            float* __restrict__ loss_out) {
    const int blk = blockIdx.x;
    const int t = threadIdx.x;
    if (blk < 64) {
        // pack B fragments: frag fr = nt*8 + s ; lane l: code n = nt*16+(l&15),
        // d = s*32 + (l>>4)*8 + e  (e = 0..7)
        const int fr = blk * 4 + (t >> 6);
        const int lane = t & 63;
        const int nt = fr >> 3, s = fr & 7;
        const int n = nt * 16 + (lane & 15);
        const int dbase = s * 32 + ((lane >> 4) << 3);
        const float* src = cb + (size_t)n * ND + dbase;
        bf16x8 vh, vl;
        #pragma unroll
        for (int e = 0; e < 8; e++) {
            float v = src[e];
            __bf16 h = (__bf16)v;
            vh[e] = h;
            vl[e] = (__bf16)(v - (float)h);
        }
        *reinterpret_cast<bf16x8*>(&wsh[(size_t)fr * 512 + lane * 8]) = vh;
        *reinterpret_cast<bf16x8*>(&wsl[(size_t)fr * 512 + lane * 8]) = vl;
    } else {
        for (int c = t; c < NK; c += 256) {
            const float4* row = reinterpret_cast<const float4*>(cb + (size_t)c * ND);
            float s = 0.f;
            #pragma unroll 8
            for (int i = 0; i < ND / 4; i++) {
                float4 v = row[i];
                s = fmaf(v.x, v.x, s); s = fmaf(v.y, v.y, s);
                s = fmaf(v.z, v.z, s); s = fmaf(v.w, v.w, s);
            }
            c2[c] = s;
        }
        if (t == 0) *loss_out = 0.f;
    }
}

__global__ __launch_bounds__(256, 2)
void vqvae_kernel(const float* __restrict__ x, const float* __restrict__ conv_w,
                  const float* __restrict__ conv_b, const float* __restrict__ gamma,
                  const float* __restrict__ beta, const float* __restrict__ mean,
                  const float* __restrict__ var, const float* __restrict__ cb,
                  const float* __restrict__ c2g,
                  const unsigned short* __restrict__ wsh,
                  const unsigned short* __restrict__ wsl,
                  float* __restrict__ out) {
    __shared__ SMem sm;
    const int t = threadIdx.x;
    const int l = t & 63;
    const int wv = t >> 6;
    const int blk = blockIdx.x;
    const int b = blk >> 8;                 // 256 tiles per image
    const int tile = blk & 255;
    const int ty0 = (tile >> 3) * TR;       // pooled-row origin (32 row tiles)
    const int tx0 = (tile & 7) * TC;        // pooled-col origin (8 col tiles)

    // ---------------- stage input halo (3 x 10 x 34, zero-padded) ------------
    {
        const int iy0 = ty0 * 2 - 1;
        const int ix0 = tx0 * 2 - 1;
        for (int e = t; e < CIN * HALO_R * HALO_C; e += 256) {
            int c = e / (HALO_R * HALO_C);
            int rem = e - c * (HALO_R * HALO_C);
            int r = rem / HALO_C;
            int cc = rem - r * HALO_C;
            int iy = iy0 + r, ix = ix0 + cc;
            float v = 0.f;
            if (iy >= 0 && iy < HIN && ix >= 0 && ix < WIN)
                v = x[(((size_t)b * CIN + c) * HIN + iy) * WIN + ix];
            sm.halo[c][r][cc] = v;
        }
        if (t == 0) sm.refine_count = 0;
    }
    __syncthreads();

    // ------------- conv3x3 + bias + maxpool2 + BN + exact GELU --------------
    // thread t owns channel d = t, loops 64 pooled positions. Produces bf16
    // hi/lo splits into swizzled LDS; accumulates sum of squares for the loss.
    {
        const int d = t;
        float w[27];
        #pragma unroll
        for (int q = 0; q < 27; q++) w[q] = conv_w[d * 27 + q];
        const float bias = conv_b[d];
        const float inv = gamma[d] / sqrtf(var[d] + BN_EPSF);
        const float mu = mean[d], bet = beta[d];
        float sq = 0.f;
        for (int pos = 0; pos < 64; pos++) {
            const int py = pos >> 4, px = pos & 15;
            const int r0 = py * 2, c0 = px * 2;
            float s00 = bias, s01 = bias, s10 = bias, s11 = bias;
            #pragma unroll
            for (int c = 0; c < 3; c++) {
                #pragma unroll
                for (int r = 0; r < 4; r++) {
                    float v0 = sm.halo[c][r0 + r][c0 + 0];
                    float v1 = sm.halo[c][r0 + r][c0 + 1];
                    float v2 = sm.halo[c][r0 + r][c0 + 2];
                    float v3 = sm.halo[c][r0 + r][c0 + 3];
                    if (r <= 2) {
                        s00 = fmaf(w[c*9 + r*3 + 0], v0, s00);
                        s00 = fmaf(w[c*9 + r*3 + 1], v1, s00);
                        s00 = fmaf(w[c*9 + r*3 + 2], v2, s00);
                        s01 = fmaf(w[c*9 + r*3 + 0], v1, s01);
                        s01 = fmaf(w[c*9 + r*3 + 1], v2, s01);
                        s01 = fmaf(w[c*9 + r*3 + 2], v3, s01);
                    }
                    if (r >= 1) {
                        s10 = fmaf(w[c*9 + (r-1)*3 + 0], v0, s10);
                        s10 = fmaf(w[c*9 + (r-1)*3 + 1], v1, s10);
                        s10 = fmaf(w[c*9 + (r-1)*3 + 2], v2, s10);
                        s11 = fmaf(w[c*9 + (r-1)*3 + 0], v1, s11);
                        s11 = fmaf(w[c*9 + (r-1)*3 + 1], v2, s11);
                        s11 = fmaf(w[c*9 + (r-1)*3 + 2], v3, s11);
                    }
                }
            }
            float m = fmaxf(fmaxf(s00, s01), fmaxf(s10, s11));
            float bn = (m - mu) * inv + bet;
            float g = 0.5f * bn * (1.0f + erff(bn * 0.7071067811865475f));
            sq = fmaf(g, g, sq);
            __bf16 h = (__bf16)g;
            __bf16 lo = (__bf16)(g - (float)h);
            int slot = pos * ND + (((d >> 3) ^ (pos & 7)) << 3) + (d & 7);
            sm.xhi[slot] = __builtin_bit_cast(unsigned short, h);
            sm.xlo[slot] = __builtin_bit_cast(unsigned short, lo);
        }
        #pragma unroll
        for (int off = 32; off; off >>= 1) sq += __shfl_xor(sq, off, 64);
        if (l == 0) sm.sqbuf[wv] = sq;
    }
    __syncthreads();

    // -------- VQ screening: dot = x.c via bf16x3-split MFMA 16x16x32 --------
    // wave wv owns codes [wv*128, wv*128+128) = 8 N-tiles; all 64 pos (4 M-tiles)
    f32x4 acc[4][8];
    #pragma unroll
    for (int i = 0; i < 4; i++)
        #pragma unroll
        for (int j = 0; j < 8; j++) acc[i][j] = (f32x4){0.f, 0.f, 0.f, 0.f};

    const bf16x8* Bhi = reinterpret_cast<const bf16x8*>(wsh);
    const bf16x8* Blo = reinterpret_cast<const bf16x8*>(wsl);

    #pragma unroll 1
    for (int s = 0; s < 8; ++s) {
        bf16x8 ah[4], al[4];
        #pragma unroll
        for (int i = 0; i < 4; ++i) {
            int m = i * 16 + (l & 15);
            int g = s * 4 + (l >> 4);
            int gp = g ^ (m & 7);
            ah[i] = *reinterpret_cast<const bf16x8*>(&sm.xhi[m * ND + gp * 8]);
            al[i] = *reinterpret_cast<const bf16x8*>(&sm.xlo[m * ND + gp * 8]);
        }
        #pragma unroll
        for (int j = 0; j < 8; ++j) {
            int f = (wv * 8 + j) * 8 + s;
            bf16x8 bh = Bhi[(size_t)f * 64 + l];
            bf16x8 bl = Blo[(size_t)f * 64 + l];
            #pragma unroll
            for (int i = 0; i < 4; ++i) {
                acc[i][j] = __builtin_amdgcn_mfma_f32_16x16x32_bf16(ah[i], bh, acc[i][j], 0, 0, 0);
                acc[i][j] = __builtin_amdgcn_mfma_f32_16x16x32_bf16(al[i], bh, acc[i][j], 0, 0, 0);
                acc[i][j] = __builtin_amdgcn_mfma_f32_16x16x32_bf16(ah[i], bl, acc[i][j], 0, 0, 0);
            }
        }
    }

    // per-lane top-2 over its 8 codes per row, butterfly over the 16-lane dim
    {
        float c2v[8];
        #pragma unroll
        for (int j = 0; j < 8; ++j) c2v[j] = c2g[(wv * 8 + j) * 16 + (l & 15)];
        #pragma unroll
        for (int i = 0; i < 4; ++i) {
            #pragma unroll
            for (int r = 0; r < 4; ++r) {
                float b1 = INFINITY, b2 = INFINITY;
                int i1 = 0x7fffffff, i2 = 0x7fffffff;
                #pragma unroll
                for (int j = 0; j < 8; ++j) {
                    float sc = 0.5f * c2v[j] - acc[i][j][r];
                    int n = (wv * 8 + j) * 16 + (l & 15);
                    top2_insert(sc, n, b1, i1, b2, i2);
                }
                for (int off = 1; off < 16; off <<= 1) {
                    float o1 = __shfl_xor(b1, off, 64);
                    int  oi1 = __shfl_xor(i1, off, 64);
                    float o2 = __shfl_xor(b2, off, 64);
                    int  oi2 = __shfl_xor(i2, off, 64);
                    top2_insert(o1, oi1, b1, i1, b2, i2);
                    top2_insert(o2, oi2, b1, i1, b2, i2);
                }
                if ((l & 15) == 0) {
                    int m = i * 16 + ((l >> 4) << 2) + r;
                    sm.ms1[wv * 64 + m] = b1; sm.ms2[wv * 64 + m] = b2;
                    sm.mi1[wv * 64 + m] = i1; sm.mi2[wv * 64 + m] = i2;
                }
            }
        }
    }
    __syncthreads();

    // cross-wave merge (waves cover disjoint code ranges)
    if (t < 64) {
        float b1 = INFINITY, b2 = INFINITY;
        int i1 = 0x7fffffff, i2 = 0x7fffffff;
        #pragma unroll
        for (int w = 0; w < 4; ++w) {
            top2_insert(sm.ms1[w * 64 + t], sm.mi1[w * 64 + t], b1, i1, b2, i2);
            top2_insert(sm.ms2[w * 64 + t], sm.mi2[w * 64 + t], b1, i1, b2, i2);
        }
        sm.bestidx[t] = i1;
        if (b2 - b1 < REFINE_EPS) {
            int slot = atomicAdd(&sm.refine_count, 1);
            if (slot < MAX_REFINE) {
                sm.refine_pos[slot] = t;
                sm.refine_c1[slot] = i1;
                sm.refine_c2[slot] = i2;
            }
        }
        // sum of best scores for the commit loss: dist = |x|^2 + 2*s1
        float s1 = b1;
        #pragma unroll
        for (int off = 32; off; off >>= 1) s1 += __shfl_xor(s1, off, 64);
        if (t == 0) sm.s1tot = s1;
    }
    __syncthreads();

    // --------- rare double-precision refinement for near-tie rows -----------
    {
        int nref = sm.refine_count;
        if (nref > MAX_REFINE) nref = MAX_REFINE;
        for (int rr = 0; rr < nref; rr++) {
            const int pos = sm.refine_pos[rr];
            const int c1 = sm.refine_c1[rr];
            const int c2r = sm.refine_c2[rr];
            const int d = t;
            const int py = pos >> 4, px = pos & 15;
            const int r0 = py * 2, c0 = px * 2;
            double s00, s01, s10, s11;
            s00 = s01 = s10 = s11 = (double)conv_b[d];
            for (int c = 0; c < 3; c++) {
                for (int r = 0; r < 4; r++) {
                    double v0 = (double)sm.halo[c][r0 + r][c0 + 0];
                    double v1 = (double)sm.halo[c][r0 + r][c0 + 1];
                    double v2 = (double)sm.halo[c][r0 + r][c0 + 2];
                    double v3 = (double)sm.halo[c][r0 + r][c0 + 3];
                    if (r <= 2) {
                        double w0 = (double)conv_w[d*27 + c*9 + r*3 + 0];
                        double w1 = (double)conv_w[d*27 + c*9 + r*3 + 1];
                        double w2 = (double)conv_w[d*27 + c*9 + r*3 + 2];
                        s00 = fma(w0, v0, s00); s00 = fma(w1, v1, s00); s00 = fma(w2, v2, s00);
                        s01 = fma(w0, v1, s01); s01 = fma(w1, v2, s01); s01 = fma(w2, v3, s01);
                    }
                    if (r >= 1) {
                        double w0 = (double)conv_w[d*27 + c*9 + (r-1)*3 + 0];
                        double w1 = (double)conv_w[d*27 + c*9 + (r-1)*3 + 1];
                        double w2 = (double)conv_w[d*27 + c*9 + (r-1)*3 + 2];
                        s10 = fma(w0, v0, s10); s10 = fma(w1, v1, s10); s10 = fma(w2, v2, s10);
                        s11 = fma(w0, v1, s11); s11 = fma(w1, v2, s11); s11 = fma(w2, v3, s11);
                    }
                }
            }
            double m = fmax(fmax(s00, s01), fmax(s10, s11));
            double bn = (m - (double)mean[d]) * ((double)gamma[d] /
                        sqrt((double)var[d] + 1e-5)) + (double)beta[d];
            double xd = 0.5 * bn * (1.0 + erf(bn * 0.70710678118654752440));
            double cv1 = (double)cb[(size_t)c1 * ND + d];
            double cv2 = (double)cb[(size_t)c2r * ND + d];
            double p1 = xd * cv1, p2 = xd * cv2;
            double q1 = cv1 * cv1, q2 = cv2 * cv2;
            for (int off = 32; off; off >>= 1) {
                p1 += __shfl_xor(p1, off, 64);
                p2 += __shfl_xor(p2, off, 64);
                q1 += __shfl_xor(q1, off, 64);
                q2 += __shfl_xor(q2, off, 64);
            }
            if ((t & 63) == 0) {
                sm.red[wv * 4 + 0] = p1; sm.red[wv * 4 + 1] = p2;
                sm.red[wv * 4 + 2] = q1; sm.red[wv * 4 + 3] = q2;
            }
            __syncthreads();
            if (t == 0) {
                double dot1 = sm.red[0] + sm.red[4] + sm.red[8] + sm.red[12];
                double dot2 = sm.red[1] + sm.red[5] + sm.red[9] + sm.red[13];
                double cs1 = sm.red[2] + sm.red[6] + sm.red[10] + sm.red[14];
                double cs2 = sm.red[3] + sm.red[7] + sm.red[11] + sm.red[15];
                double sc1 = 0.5 * cs1 - dot1;
                double sc2 = 0.5 * cs2 - dot2;
                bool take1 = (sc1 < sc2) || (sc1 == sc2 && c1 < c2r);
                sm.bestidx[pos] = take1 ? c1 : c2r;
            }
            __syncthreads();
        }
    }
    __syncthreads();

    // --------------- write indices, quant (NCHW, 64B runs), loss ------------
    if (t < 64) {
        const int py = t >> 4, px = t & 15;
        const int hw = (ty0 + py) * WP + tx0 + px;
        out[QOUT + (size_t)b * NPOS + hw] = (float)sm.bestidx[t];
    }
    {
        // wave wv handles pooled row py = wv; lane: px = l&15, d-quad = l>>4
        const int px = l & 15, dq = l >> 4;
        const int pos = wv * 16 + px;
        const int code = sm.bestidx[pos];
        const int hw = (ty0 + wv) * WP + tx0 + px;
        const float* crow = cb + (size_t)code * ND;
        float* qb = out + (size_t)b * ND * NPOS + hw;
        #pragma unroll
        for (int kk = 0; kk < 16; ++kk) {
            const int d0 = dq * 64 + kk * 4;
            float4 cv = *reinterpret_cast<const float4*>(&crow[d0]);
            qb[(size_t)(d0 + 0) * NPOS] = cv.x;
            qb[(size_t)(d0 + 1) * NPOS] = cv.y;
            qb[(size_t)(d0 + 2) * NPOS] = cv.z;
            qb[(size_t)(d0 + 3) * NPOS] = cv.w;
        }
    }
    if (t == 0) {
        float tot = sm.sqbuf[0] + sm.sqbuf[1] + sm.sqbuf[2] + sm.sqbuf[3]
                  + 2.0f * sm.s1tot;
        atomicAdd(out + LOSS_OFF, tot * (1.0f / 67108864.0f));
    }
}

extern "C" void kernel_launch(void* const* d_in, const int* in_sizes, int n_in,
                              void* d_out, int out_size, void* d_ws, size_t ws_size,
                              hipStream_t stream) {
    const float* x      = (const float*)d_in[0];
    const float* conv_w = (const float*)d_in[1];
    const float* conv_b = (const float*)d_in[2];
    const float* gammap = (const float*)d_in[3];
    const float* betap  = (const float*)d_in[4];
    const float* meanp  = (const float*)d_in[5];
    const float* varp   = (const float*)d_in[6];
    const float* cb     = (const float*)d_in[7];
    float* out = (float*)d_out;

    float* c2w = (float*)d_ws;
    unsigned short* wsh = (unsigned short*)d_ws + WS_HI_SHORT_OFF;
    unsigned short* wsl = (unsigned short*)d_ws + WS_LO_SHORT_OFF;

    prep_kernel<<<65, 256, 0, stream>>>(cb, c2w, wsh, wsl, out + LOSS_OFF);
    vqvae_kernel<<<NB * 256, 256, 0, stream>>>(x, conv_w, conv_b, gammap, betap,
                                               meanp, varp, cb, c2w, wsh, wsl, out);
}

// Round 3
// 788.179 us; speedup vs baseline: 4.0441x; 1.2561x over previous
//
#include <hip/hip_runtime.h>
#include <math.h>

#define CIN 3
#define HIN 256
#define WIN 256
#define ND 256
#define NK 512
#define HP 128
#define WP 128
#define NPOS (HP*WP)
#define NB 16
#define QOUT ((size_t)NB*(size_t)ND*(size_t)NPOS)      // 67108864
#define IDXOUT ((size_t)NB*(size_t)NPOS)               // 262144
#define LOSS_OFF (QOUT + IDXOUT)
#define REFINE_EPS 0.02f
#define MAX_REFINE 16
#define BN_EPSF 1e-5f

// tile: 2 pooled rows x 32 pooled cols = 64 positions per block
#define HR 6
#define HC 66
#define HALO_N (CIN*HR*HC)    // 1188

typedef __bf16 bf16x8 __attribute__((ext_vector_type(8)));
typedef float  f32x4  __attribute__((ext_vector_type(4)));

// ws layout:
//   float  c2[512]                        @ float 0
//   short  vq_hi[256*512]                 @ short 1024
//   short  vq_lo[256*512]                 @ short 132096
//   short  cw_hi[16*512]                  @ short 263168
//   short  cw_lo[16*512]                  @ short 271360
//   float  scale[256]                     @ float 139776
//   float  shift[256]                     @ float 140032
#define WS_VQH_S 1024
#define WS_VQL_S 132096
#define WS_CWH_S 263168
#define WS_CWL_S 271360
#define WS_SC_F  139776
#define WS_SH_F  140032

struct SMem {
    alignas(16) unsigned short xhi[64 * ND];   // 32 KiB, 16B-group XOR swizzle
    alignas(16) unsigned short xlo[64 * ND];   // 32 KiB
    float halo[HALO_N];                        // 4.6 KiB (persists for refine)
    float ms1[4 * 64];
    float ms2[4 * 64];
    int   mi1[4 * 64];
    int   mi2[4 * 64];
    int   bestidx[64];
    int   refine_pos[MAX_REFINE];
    int   refine_c1[MAX_REFINE];
    int   refine_c2[MAX_REFINE];
    int   refine_count;
    float sqbuf[4];
    float s1tot;
    double red[16];
};

__device__ __forceinline__ void top2_insert(float s, int c,
                                            float& b1, int& i1,
                                            float& b2, int& i2) {
    if (c == i1) {                      // dedupe: same candidate as current best
        if (s < b1) b1 = s;
        return;
    }
    bool better1 = (s < b1) || (s == b1 && c < i1);
    if (better1) { b2 = b1; i2 = i1; b1 = s; i1 = c; }
    else {
        bool better2 = (s < b2) || (s == b2 && c < i2);
        if (better2) { b2 = s; i2 = c; }
    }
}

__global__ void prep_kernel(const float* __restrict__ cb,
                            const float* __restrict__ conv_w,
                            const float* __restrict__ conv_b,
                            const float* __restrict__ gamma,
                            const float* __restrict__ beta,
                            const float* __restrict__ mean,
                            const float* __restrict__ var,
                            float* __restrict__ c2,
                            unsigned short* __restrict__ vqh,
                            unsigned short* __restrict__ vql,
                            unsigned short* __restrict__ cwh,
                            unsigned short* __restrict__ cwl,
                            float* __restrict__ scale,
                            float* __restrict__ shift,
                            float* __restrict__ loss_out) {
    const int blk = blockIdx.x;
    const int t = threadIdx.x;
    if (blk < 64) {
        // VQ B fragments: frag fr = nt*8 + s ; lane l: code n = nt*16+(l&15),
        // d = s*32 + (l>>4)*8 + e
        const int fr = blk * 4 + (t >> 6);
        const int lane = t & 63;
        const int nt = fr >> 3, s = fr & 7;
        const int n = nt * 16 + (lane & 15);
        const int dbase = s * 32 + ((lane >> 4) << 3);
        const float* src = cb + (size_t)n * ND + dbase;
        bf16x8 vh, vl;
        #pragma unroll
        for (int e = 0; e < 8; e++) {
            float v = src[e];
            __bf16 h = (__bf16)v;
            vh[e] = h;
            vl[e] = (__bf16)(v - (float)h);
        }
        *reinterpret_cast<bf16x8*>(&vqh[(size_t)fr * 512 + lane * 8]) = vh;
        *reinterpret_cast<bf16x8*>(&vql[(size_t)fr * 512 + lane * 8]) = vl;
    } else if (blk == 64) {
        for (int c = t; c < NK; c += 256) {
            const float4* row = reinterpret_cast<const float4*>(cb + (size_t)c * ND);
            float s = 0.f;
            #pragma unroll 8
            for (int i = 0; i < ND / 4; i++) {
                float4 v = row[i];
                s = fmaf(v.x, v.x, s); s = fmaf(v.y, v.y, s);
                s = fmaf(v.z, v.z, s); s = fmaf(v.w, v.w, s);
            }
            c2[c] = s;
        }
        {
            int ch = t;
            float inv = gamma[ch] / sqrtf(var[ch] + BN_EPSF);
            scale[ch] = inv;
            shift[ch] = (conv_b[ch] - mean[ch]) * inv + beta[ch];
        }
        if (t == 0) *loss_out = 0.f;
    } else {
        // conv-weight B fragments: 16 N-tiles, K=32 (27 real + 5 zero)
        const int lane = t & 63;
        for (int fr = t >> 6; fr < 16; fr += 4) {
            const int n = fr * 16 + (lane & 15);
            bf16x8 vh, vl;
            #pragma unroll
            for (int e = 0; e < 8; e++) {
                int k = ((lane >> 4) << 3) + e;
                float v = (k < 27) ? conv_w[n * 27 + k] : 0.f;
                __bf16 h = (__bf16)v;
                vh[e] = h;
                vl[e] = (__bf16)(v - (float)h);
            }
            *reinterpret_cast<bf16x8*>(&cwh[(size_t)fr * 512 + lane * 8]) = vh;
            *reinterpret_cast<bf16x8*>(&cwl[(size_t)fr * 512 + lane * 8]) = vl;
        }
    }
}

__global__ __launch_bounds__(256, 2)
void vqvae_kernel(const float* __restrict__ x, const float* __restrict__ conv_w,
                  const float* __restrict__ conv_b, const float* __restrict__ gamma,
                  const float* __restrict__ beta, const float* __restrict__ mean,
                  const float* __restrict__ var, const float* __restrict__ cb,
                  const float* __restrict__ c2g,
                  const unsigned short* __restrict__ vqh,
                  const unsigned short* __restrict__ vql,
                  const unsigned short* __restrict__ cwh,
                  const unsigned short* __restrict__ cwl,
                  const float* __restrict__ scale,
                  const float* __restrict__ shift,
                  float* __restrict__ out) {
    __shared__ SMem sm;
    const int t = threadIdx.x;
    const int l = t & 63;
    const int wv = t >> 6;
    const int blk = blockIdx.x;
    const int b = blk >> 8;                 // 256 tiles per image
    const int tile = blk & 255;
    const int ty0 = (tile >> 2) * 2;        // pooled-row origin (64 row tiles)
    const int tx0 = (tile & 3) * 32;        // pooled-col origin (4 col tiles)

    // ---------------- stage input halo (3 x 6 x 66, zero-padded) -------------
    {
        const int iy0 = ty0 * 2 - 1;
        const int ix0 = tx0 * 2 - 1;
        for (int e = t; e < HALO_N; e += 256) {
            int c = e / (HR * HC);
            int rem = e - c * (HR * HC);
            int r = rem / HC;
            int cc = rem - r * HC;
            int iy = iy0 + r, ix = ix0 + cc;
            float v = 0.f;
            if (iy >= 0 && iy < HIN && ix >= 0 && ix < WIN)
                v = x[(((size_t)b * CIN + c) * HIN + iy) * WIN + ix];
            sm.halo[e] = v;
        }
        if (t == 0) sm.refine_count = 0;
    }

    // per-lane k -> halo-offset table (k = (l>>4)*8 + e)
    int hoff[8];
    #pragma unroll
    for (int e = 0; e < 8; e++) {
        int k = ((l >> 4) << 3) + e;
        int c = k / 9;
        int r9 = k - c * 9;
        int dy = r9 / 3;
        int dx = r9 - dy * 3;
        hoff[e] = (k < 27) ? (c * (HR * HC) + dy * HC + dx) : 0;
    }

    // conv-weight fragments + folded BN for this wave's 64 channels
    bf16x8 bwh[4], bwl[4];
    float sc4[4], sh4[4];
    #pragma unroll
    for (int j = 0; j < 4; j++) {
        int nt = wv * 4 + j;
        bwh[j] = *reinterpret_cast<const bf16x8*>(&cwh[nt * 512 + l * 8]);
        bwl[j] = *reinterpret_cast<const bf16x8*>(&cwl[nt * 512 + l * 8]);
        int ch = wv * 64 + j * 16 + (l & 15);
        sc4[j] = scale[ch];
        sh4[j] = shift[ch];
    }
    __syncthreads();

    // -------- conv3x3 via im2col MFMA + maxpool + BN + GELU -> xe LDS --------
    // chunk mc: 16 pooled positions (pos = mc*16 + p), conv m = p*4 + q
    float sq = 0.f;
    #pragma unroll 1
    for (int mc = 0; mc < 4; mc++) {
        bf16x8 ah[4], al[4];
        #pragma unroll
        for (int i = 0; i < 4; i++) {
            const int m16 = l & 15;
            const int p = i * 4 + (m16 >> 2);
            const int q = m16 & 3;
            const int pos = mc * 16 + p;
            const int py = pos >> 5, px = pos & 31;
            const int cy = py * 2 + (q >> 1), cx = px * 2 + (q & 1);
            const int base = cy * HC + cx;
            #pragma unroll
            for (int e = 0; e < 8; e++) {
                float v = sm.halo[base + hoff[e]];   // k>=27 lanes read junk,
                __bf16 h = (__bf16)v;                // zeroed by zero weights
                ah[i][e] = h;
                al[i][e] = (__bf16)(v - (float)h);
            }
        }
        f32x4 acc[4][4];
        #pragma unroll
        for (int i = 0; i < 4; i++)
            #pragma unroll
            for (int j = 0; j < 4; j++) acc[i][j] = (f32x4){0.f, 0.f, 0.f, 0.f};
        #pragma unroll
        for (int j = 0; j < 4; j++) {
            #pragma unroll
            for (int i = 0; i < 4; i++) {
                acc[i][j] = __builtin_amdgcn_mfma_f32_16x16x32_bf16(ah[i], bwh[j], acc[i][j], 0, 0, 0);
                acc[i][j] = __builtin_amdgcn_mfma_f32_16x16x32_bf16(al[i], bwh[j], acc[i][j], 0, 0, 0);
                acc[i][j] = __builtin_amdgcn_mfma_f32_16x16x32_bf16(ah[i], bwl[j], acc[i][j], 0, 0, 0);
            }
        }
        // maxpool(4 regs) + BN + exact GELU, write bf16 hi/lo to swizzled LDS
        #pragma unroll
        for (int i = 0; i < 4; i++) {
            const int pos = mc * 16 + i * 4 + (l >> 4);
            #pragma unroll
            for (int j = 0; j < 4; j++) {
                f32x4 a4 = acc[i][j];
                float m = fmaxf(fmaxf(a4[0], a4[1]), fmaxf(a4[2], a4[3]));
                float bn = fmaf(m, sc4[j], sh4[j]);
                float g = 0.5f * bn * (1.0f + erff(bn * 0.7071067811865475f));
                sq = fmaf(g, g, sq);
                __bf16 h = (__bf16)g;
                __bf16 lo = (__bf16)(g - (float)h);
                int ch = wv * 64 + j * 16 + (l & 15);
                int slot = pos * ND + ((((ch >> 3) ^ (pos & 7)) << 3)) + (ch & 7);
                sm.xhi[slot] = __builtin_bit_cast(unsigned short, h);
                sm.xlo[slot] = __builtin_bit_cast(unsigned short, lo);
            }
        }
    }
    #pragma unroll
    for (int off = 32; off; off >>= 1) sq += __shfl_xor(sq, off, 64);
    if (l == 0) sm.sqbuf[wv] = sq;
    __syncthreads();

    // -------- VQ screening: dot = x.c via bf16x3-split MFMA 16x16x32 --------
    f32x4 acc[4][8];
    #pragma unroll
    for (int i = 0; i < 4; i++)
        #pragma unroll
        for (int j = 0; j < 8; j++) acc[i][j] = (f32x4){0.f, 0.f, 0.f, 0.f};

    const bf16x8* Bhi = reinterpret_cast<const bf16x8*>(vqh);
    const bf16x8* Blo = reinterpret_cast<const bf16x8*>(vql);

    #pragma unroll 1
    for (int s = 0; s < 8; ++s) {
        bf16x8 ah[4], al[4];
        #pragma unroll
        for (int i = 0; i < 4; ++i) {
            int m = i * 16 + (l & 15);
            int g = s * 4 + (l >> 4);
            int gp = g ^ (m & 7);
            ah[i] = *reinterpret_cast<const bf16x8*>(&sm.xhi[m * ND + gp * 8]);
            al[i] = *reinterpret_cast<const bf16x8*>(&sm.xlo[m * ND + gp * 8]);
        }
        #pragma unroll
        for (int j = 0; j < 8; ++j) {
            int f = (wv * 8 + j) * 8 + s;
            bf16x8 bh = Bhi[(size_t)f * 64 + l];
            bf16x8 bl = Blo[(size_t)f * 64 + l];
            #pragma unroll
            for (int i = 0; i < 4; ++i) {
                acc[i][j] = __builtin_amdgcn_mfma_f32_16x16x32_bf16(ah[i], bh, acc[i][j], 0, 0, 0);
                acc[i][j] = __builtin_amdgcn_mfma_f32_16x16x32_bf16(al[i], bh, acc[i][j], 0, 0, 0);
                acc[i][j] = __builtin_amdgcn_mfma_f32_16x16x32_bf16(ah[i], bl, acc[i][j], 0, 0, 0);
            }
        }
    }

    // per-lane top-2 over its 8 codes per row, butterfly over the 16-lane dim
    {
        float c2v[8];
        #pragma unroll
        for (int j = 0; j < 8; ++j) c2v[j] = c2g[(wv * 8 + j) * 16 + (l & 15)];
        #pragma unroll
        for (int i = 0; i < 4; ++i) {
            #pragma unroll
            for (int r = 0; r < 4; ++r) {
                float b1 = INFINITY, b2 = INFINITY;
                int i1 = 0x7fffffff, i2 = 0x7fffffff;
                #pragma unroll
                for (int j = 0; j < 8; ++j) {
                    float sc = 0.5f * c2v[j] - acc[i][j][r];
                    int n = (wv * 8 + j) * 16 + (l & 15);
                    top2_insert(sc, n, b1, i1, b2, i2);
                }
                for (int off = 1; off < 16; off <<= 1) {
                    float o1 = __shfl_xor(b1, off, 64);
                    int  oi1 = __shfl_xor(i1, off, 64);
                    float o2 = __shfl_xor(b2, off, 64);
                    int  oi2 = __shfl_xor(i2, off, 64);
                    top2_insert(o1, oi1, b1, i1, b2, i2);
                    top2_insert(o2, oi2, b1, i1, b2, i2);
                }
                if ((l & 15) == 0) {
                    int m = i * 16 + ((l >> 4) << 2) + r;
                    sm.ms1[wv * 64 + m] = b1; sm.ms2[wv * 64 + m] = b2;
                    sm.mi1[wv * 64 + m] = i1; sm.mi2[wv * 64 + m] = i2;
                }
            }
        }
    }
    __syncthreads();

    // cross-wave merge (waves cover disjoint code ranges)
    if (t < 64) {
        float b1 = INFINITY, b2 = INFINITY;
        int i1 = 0x7fffffff, i2 = 0x7fffffff;
        #pragma unroll
        for (int w = 0; w < 4; ++w) {
            top2_insert(sm.ms1[w * 64 + t], sm.mi1[w * 64 + t], b1, i1, b2, i2);
            top2_insert(sm.ms2[w * 64 + t], sm.mi2[w * 64 + t], b1, i1, b2, i2);
        }
        sm.bestidx[t] = i1;
        if (b2 - b1 < REFINE_EPS) {
            int slot = atomicAdd(&sm.refine_count, 1);
            if (slot < MAX_REFINE) {
                sm.refine_pos[slot] = t;
                sm.refine_c1[slot] = i1;
                sm.refine_c2[slot] = i2;
            }
        }
        float s1 = b1;
        #pragma unroll
        for (int off = 32; off; off >>= 1) s1 += __shfl_xor(s1, off, 64);
        if (t == 0) sm.s1tot = s1;
    }
    __syncthreads();

    // --------- rare double-precision refinement for near-tie rows -----------
    {
        int nref = sm.refine_count;
        if (nref > MAX_REFINE) nref = MAX_REFINE;
        for (int rr = 0; rr < nref; rr++) {
            const int pos = sm.refine_pos[rr];
            const int c1 = sm.refine_c1[rr];
            const int c2r = sm.refine_c2[rr];
            const int d = t;
            const int py = pos >> 5, px = pos & 31;
            const int r0 = py * 2, c0 = px * 2;
            double s00, s01, s10, s11;
            s00 = s01 = s10 = s11 = (double)conv_b[d];
            for (int c = 0; c < 3; c++) {
                for (int r = 0; r < 4; r++) {
                    const float* hrow = &sm.halo[c * (HR * HC) + (r0 + r) * HC + c0];
                    double v0 = (double)hrow[0];
                    double v1 = (double)hrow[1];
                    double v2 = (double)hrow[2];
                    double v3 = (double)hrow[3];
                    if (r <= 2) {
                        double w0 = (double)conv_w[d*27 + c*9 + r*3 + 0];
                        double w1 = (double)conv_w[d*27 + c*9 + r*3 + 1];
                        double w2 = (double)conv_w[d*27 + c*9 + r*3 + 2];
                        s00 = fma(w0, v0, s00); s00 = fma(w1, v1, s00); s00 = fma(w2, v2, s00);
                        s01 = fma(w0, v1, s01); s01 = fma(w1, v2, s01); s01 = fma(w2, v3, s01);
                    }
                    if (r >= 1) {
                        double w0 = (double)conv_w[d*27 + c*9 + (r-1)*3 + 0];
                        double w1 = (double)conv_w[d*27 + c*9 + (r-1)*3 + 1];
                        double w2 = (double)conv_w[d*27 + c*9 + (r-1)*3 + 2];
                        s10 = fma(w0, v0, s10); s10 = fma(w1, v1, s10); s10 = fma(w2, v2, s10);
                        s11 = fma(w0, v1, s11); s11 = fma(w1, v2, s11); s11 = fma(w2, v3, s11);
                    }
                }
            }
            double m = fmax(fmax(s00, s01), fmax(s10, s11));
            double bn = (m - (double)mean[d]) * ((double)gamma[d] /
                        sqrt((double)var[d] + 1e-5)) + (double)beta[d];
            double xd = 0.5 * bn * (1.0 + erf(bn * 0.70710678118654752440));
            double cv1 = (double)cb[(size_t)c1 * ND + d];
            double cv2 = (double)cb[(size_t)c2r * ND + d];
            double p1 = xd * cv1, p2 = xd * cv2;
            double q1 = cv1 * cv1, q2 = cv2 * cv2;
            for (int off = 32; off; off >>= 1) {
                p1 += __shfl_xor(p1, off, 64);
                p2 += __shfl_xor(p2, off, 64);
                q1 += __shfl_xor(q1, off, 64);
                q2 += __shfl_xor(q2, off, 64);
            }
            if ((t & 63) == 0) {
                sm.red[wv * 4 + 0] = p1; sm.red[wv * 4 + 1] = p2;
                sm.red[wv * 4 + 2] = q1; sm.red[wv * 4 + 3] = q2;
            }
            __syncthreads();
            if (t == 0) {
                double dot1 = sm.red[0] + sm.red[4] + sm.red[8] + sm.red[12];
                double dot2 = sm.red[1] + sm.red[5] + sm.red[9] + sm.red[13];
                double cs1 = sm.red[2] + sm.red[6] + sm.red[10] + sm.red[14];
                double cs2 = sm.red[3] + sm.red[7] + sm.red[11] + sm.red[15];
                double sc1 = 0.5 * cs1 - dot1;
                double sc2 = 0.5 * cs2 - dot2;
                bool take1 = (sc1 < sc2) || (sc1 == sc2 && c1 < c2r);
                sm.bestidx[pos] = take1 ? c1 : c2r;
            }
            __syncthreads();
        }
    }
    __syncthreads();

    // --------------- write indices, quant (NCHW, 128B runs), loss -----------
    if (t < 64) {
        const int hw = (ty0 + (t >> 5)) * WP + tx0 + (t & 31);
        out[QOUT + (size_t)b * NPOS + hw] = (float)sm.bestidx[t];
    }
    {
        // wave wv: channels [wv*64, wv*64+64); lane = pooled position
        const int code = sm.bestidx[l];
        const int hw = (ty0 + (l >> 5)) * WP + tx0 + (l & 31);
        const float* crow = cb + (size_t)code * ND + wv * 64;
        float* qb = out + (size_t)b * ND * NPOS + hw;
        #pragma unroll
        for (int k4 = 0; k4 < 16; ++k4) {
            float4 cv = *reinterpret_cast<const float4*>(&crow[k4 * 4]);
            const size_t d0 = (size_t)(wv * 64 + k4 * 4);
            qb[(d0 + 0) * NPOS] = cv.x;
            qb[(d0 + 1) * NPOS] = cv.y;
            qb[(d0 + 2) * NPOS] = cv.z;
            qb[(d0 + 3) * NPOS] = cv.w;
        }
    }
    if (t == 0) {
        float tot = sm.sqbuf[0] + sm.sqbuf[1] + sm.sqbuf[2] + sm.sqbuf[3]
                  + 2.0f * sm.s1tot;
        atomicAdd(out + LOSS_OFF, tot * (1.0f / 67108864.0f));
    }
}

extern "C" void kernel_launch(void* const* d_in, const int* in_sizes, int n_in,
                              void* d_out, int out_size, void* d_ws, size_t ws_size,
                              hipStream_t stream) {
    const float* x      = (const float*)d_in[0];
    const float* conv_w = (const float*)d_in[1];
    const float* conv_b = (const float*)d_in[2];
    const float* gammap = (const float*)d_in[3];
    const float* betap  = (const float*)d_in[4];
    const float* meanp  = (const float*)d_in[5];
    const float* varp   = (const float*)d_in[6];
    const float* cb     = (const float*)d_in[7];
    float* out = (float*)d_out;

    float* c2w = (float*)d_ws;
    unsigned short* vqh = (unsigned short*)d_ws + WS_VQH_S;
    unsigned short* vql = (unsigned short*)d_ws + WS_VQL_S;
    unsigned short* cwh = (unsigned short*)d_ws + WS_CWH_S;
    unsigned short* cwl = (unsigned short*)d_ws + WS_CWL_S;
    float* scalep = (float*)d_ws + WS_SC_F;
    float* shiftp = (float*)d_ws + WS_SH_F;

    prep_kernel<<<66, 256, 0, stream>>>(cb, conv_w, conv_b, gammap, betap,
                                        meanp, varp, c2w, vqh, vql, cwh, cwl,
                                        scalep, shiftp, out + LOSS_OFF);
    vqvae_kernel<<<NB * 256, 256, 0, stream>>>(x, conv_w, conv_b, gammap, betap,
                                               meanp, varp, cb, c2w, vqh, vql,
                                               cwh, cwl, scalep, shiftp, out);
}

// Round 4
// 677.974 us; speedup vs baseline: 4.7014x; 1.1626x over previous
//
#include <hip/hip_runtime.h>
#include <math.h>

#define CIN 3
#define HIN 256
#define WIN 256
#define ND 256
#define NK 512
#define HP 128
#define WP 128
#define NPOS (HP*WP)
#define NB 16
#define QOUT ((size_t)NB*(size_t)ND*(size_t)NPOS)      // 67108864
#define IDXOUT ((size_t)NB*(size_t)NPOS)               // 262144
#define LOSS_OFF (QOUT + IDXOUT)
#define REFINE_EPS 0.05f
#define MAX_REFINE 16
#define BN_EPSF 1e-5f
#define SSHIFT 128.0f

// tile: 2 pooled rows x 32 pooled cols = 64 positions per block
#define HR 6
#define HC 66
#define HCH 70                 // padded stride for fp16 halo
#define HALO_N (CIN*HR*HC)     // 1188

typedef _Float16 f16x8 __attribute__((ext_vector_type(8)));
typedef float    f32x4 __attribute__((ext_vector_type(4)));

// ws byte layout: c2 f32[512] @0 ; vqh f16[256*512] @2048 ; cwh f16[16*512]
// @264192 ; scale f32[256] @280576 ; shift f32[256] @281600
#define WS_VQH_B 2048
#define WS_CWH_B 264192
#define WS_SC_B  280576
#define WS_SH_B  281600

struct SMem {
    alignas(16) unsigned short xe[64 * ND];    // fp16 bits, swizzled, 32 KiB
    float halo[HALO_N];                        // fp32 halo (refine), 4.6 KiB
    _Float16 halo_h[CIN * HR * HCH];           // fp16 halo (conv A), 2.5 KiB
    unsigned int ms1[4 * 64];                  // packed top-3 per wave
    unsigned int ms2[4 * 64];
    unsigned int ms3[4 * 64];
    int   bestidx[64];
    int   refine_pos[MAX_REFINE];
    int   refine_c[MAX_REFINE][3];
    int   refine_count;
    float sqbuf[4];
    float s1tot;
    double red[32];
};

__device__ __forceinline__ unsigned pack_score(float s, int n) {
    unsigned b = __builtin_bit_cast(unsigned, s);
    b ^= (unsigned)(((int)b >> 31) | 0x80000000);
    return (b & 0xFFFFFE00u) | (unsigned)n;
}
__device__ __forceinline__ float unpack_score(unsigned u) {
    unsigned e = u & 0xFFFFFE00u;
    unsigned b = (e & 0x80000000u) ? (e ^ 0x80000000u) : ~e;
    return __builtin_bit_cast(float, b);
}
__device__ __forceinline__ void insert3(unsigned u, unsigned& b1,
                                        unsigned& b2, unsigned& b3) {
    unsigned t1 = min(u, b1), h1 = max(u, b1);
    b1 = t1;
    unsigned t2 = min(h1, b2), h2 = max(h1, b2);
    b2 = t2;
    b3 = min(h2, b3);
}

__global__ void prep_kernel(const float* __restrict__ cb,
                            const float* __restrict__ conv_w,
                            const float* __restrict__ conv_b,
                            const float* __restrict__ gamma,
                            const float* __restrict__ beta,
                            const float* __restrict__ mean,
                            const float* __restrict__ var,
                            float* __restrict__ c2,
                            _Float16* __restrict__ vqh,
                            _Float16* __restrict__ cwh,
                            float* __restrict__ scale,
                            float* __restrict__ shift,
                            float* __restrict__ loss_out) {
    const int blk = blockIdx.x;
    const int t = threadIdx.x;
    if (blk < 64) {
        // VQ B fragments (fp16): frag fr = nt*8 + s; lane l: code n =
        // nt*16+(l&15), d = s*32 + (l>>4)*8 + e
        const int fr = blk * 4 + (t >> 6);
        const int lane = t & 63;
        const int nt = fr >> 3, s = fr & 7;
        const int n = nt * 16 + (lane & 15);
        const int dbase = s * 32 + ((lane >> 4) << 3);
        const float* src = cb + (size_t)n * ND + dbase;
        f16x8 vh;
        #pragma unroll
        for (int e = 0; e < 8; e++) vh[e] = (_Float16)src[e];
        *reinterpret_cast<f16x8*>(&vqh[(size_t)fr * 512 + lane * 8]) = vh;
    } else if (blk == 64) {
        for (int c = t; c < NK; c += 256) {
            const float4* row = reinterpret_cast<const float4*>(cb + (size_t)c * ND);
            float s = 0.f;
            #pragma unroll 8
            for (int i = 0; i < ND / 4; i++) {
                float4 v = row[i];
                s = fmaf(v.x, v.x, s); s = fmaf(v.y, v.y, s);
                s = fmaf(v.z, v.z, s); s = fmaf(v.w, v.w, s);
            }
            c2[c] = s;
        }
        {
            int ch = t;
            float inv = gamma[ch] / sqrtf(var[ch] + BN_EPSF);
            scale[ch] = inv;
            shift[ch] = (conv_b[ch] - mean[ch]) * inv + beta[ch];
        }
        if (t == 0) *loss_out = 0.f;
    } else {
        // conv-weight fragments (fp16): 16 N-tiles, K=32 (27 real + 5 zero)
        const int lane = t & 63;
        for (int fr = t >> 6; fr < 16; fr += 4) {
            const int n = fr * 16 + (lane & 15);
            f16x8 vh;
            #pragma unroll
            for (int e = 0; e < 8; e++) {
                int k = ((lane >> 4) << 3) + e;
                vh[e] = (k < 27) ? (_Float16)conv_w[n * 27 + k] : (_Float16)0.f;
            }
            *reinterpret_cast<f16x8*>(&cwh[(size_t)fr * 512 + lane * 8]) = vh;
        }
    }
}

__global__ __launch_bounds__(256, 3)
void vqvae_kernel(const float* __restrict__ x, const float* __restrict__ conv_w,
                  const float* __restrict__ cb, const float* __restrict__ c2g,
                  const float* __restrict__ conv_bp,
                  const float* __restrict__ gamma, const float* __restrict__ beta,
                  const float* __restrict__ mean, const float* __restrict__ var,
                  const _Float16* __restrict__ vqh,
                  const _Float16* __restrict__ cwh,
                  const float* __restrict__ scale,
                  const float* __restrict__ shift,
                  float* __restrict__ out) {
    __shared__ SMem sm;
    const int t = threadIdx.x;
    const int l = t & 63;
    const int wv = t >> 6;
    const int blk = blockIdx.x;
    const int b = blk >> 8;
    const int tile = blk & 255;
    const int ty0 = (tile >> 2) * 2;        // pooled-row origin
    const int tx0 = (tile & 3) * 32;        // pooled-col origin

    // -------------- stage input halo fp32 + fp16 (zero-padded) --------------
    {
        const int iy0 = ty0 * 2 - 1;
        const int ix0 = tx0 * 2 - 1;
        for (int e = t; e < HALO_N; e += 256) {
            int c = e / (HR * HC);
            int rem = e - c * (HR * HC);
            int r = rem / HC;
            int cc = rem - r * HC;
            int iy = iy0 + r, ix = ix0 + cc;
            float v = 0.f;
            if (iy >= 0 && iy < HIN && ix >= 0 && ix < WIN)
                v = x[(((size_t)b * CIN + c) * HIN + iy) * WIN + ix];
            sm.halo[e] = v;
            sm.halo_h[c * (HR * HCH) + r * HCH + cc] = (_Float16)v;
        }
        if (t == 0) sm.refine_count = 0;
    }

    // per-lane k -> fp16-halo offset (k = (l>>4)*8 + e)
    int hoff2[8];
    #pragma unroll
    for (int e = 0; e < 8; e++) {
        int k = ((l >> 4) << 3) + e;
        int c = k / 9;
        int r9 = k - c * 9;
        int dy = r9 / 3;
        int dx = r9 - dy * 3;
        hoff2[e] = (k < 27) ? (c * (HR * HCH) + dy * HCH + dx) : 0;
    }

    // conv-weight fragments + folded BN for this wave's 64 channels
    f16x8 bwh[4];
    float sc4[4], sh4[4];
    #pragma unroll
    for (int j = 0; j < 4; j++) {
        int nt = wv * 4 + j;
        bwh[j] = *reinterpret_cast<const f16x8*>(&cwh[nt * 512 + l * 8]);
        int ch = wv * 64 + j * 16 + (l & 15);
        sc4[j] = scale[ch];
        sh4[j] = shift[ch];
    }
    __syncthreads();

    // ------- conv3x3 via im2col fp16 MFMA + maxpool + BN + exact GELU -------
    float sq = 0.f;
    #pragma unroll 1
    for (int mc = 0; mc < 4; mc++) {
        f16x8 ah[4];
        #pragma unroll
        for (int i = 0; i < 4; i++) {
            const int m16 = l & 15;
            const int p = i * 4 + (m16 >> 2);
            const int q = m16 & 3;
            const int pos = mc * 16 + p;
            const int py = pos >> 5, px = pos & 31;
            const int cy = py * 2 + (q >> 1), cx = px * 2 + (q & 1);
            const int base = cy * HCH + cx;
            #pragma unroll
            for (int e = 0; e < 8; e++)
                ah[i][e] = sm.halo_h[base + hoff2[e]];  // k>=27: junk x zero-w
        }
        f32x4 acc[4][4];
        #pragma unroll
        for (int i = 0; i < 4; i++)
            #pragma unroll
            for (int j = 0; j < 4; j++) acc[i][j] = (f32x4){0.f, 0.f, 0.f, 0.f};
        #pragma unroll
        for (int j = 0; j < 4; j++)
            #pragma unroll
            for (int i = 0; i < 4; i++)
                acc[i][j] = __builtin_amdgcn_mfma_f32_16x16x32_f16(ah[i], bwh[j], acc[i][j], 0, 0, 0);
        #pragma unroll
        for (int i = 0; i < 4; i++) {
            const int pos = mc * 16 + i * 4 + (l >> 4);
            #pragma unroll
            for (int j = 0; j < 4; j++) {
                f32x4 a4 = acc[i][j];
                float m = fmaxf(fmaxf(a4[0], a4[1]), fmaxf(a4[2], a4[3]));
                float bn = fmaf(m, sc4[j], sh4[j]);
                float g = 0.5f * bn * (1.0f + erff(bn * 0.7071067811865475f));
                sq = fmaf(g, g, sq);
                _Float16 h = (_Float16)g;
                int ch = wv * 64 + j * 16 + (l & 15);
                int slot = pos * ND + (((ch >> 3) ^ (pos & 7)) << 3) + (ch & 7);
                sm.xe[slot] = __builtin_bit_cast(unsigned short, h);
            }
        }
    }
    #pragma unroll
    for (int off = 32; off; off >>= 1) sq += __shfl_xor(sq, off, 64);
    if (l == 0) sm.sqbuf[wv] = sq;
    __syncthreads();

    // -------- VQ screening: single-term fp16 MFMA, packed top-3 -------------
    unsigned pb1[4][4], pb2[4][4], pb3[4][4];
    #pragma unroll
    for (int i = 0; i < 4; i++)
        #pragma unroll
        for (int r = 0; r < 4; r++) {
            pb1[i][r] = 0xFFFFFFFFu; pb2[i][r] = 0xFFFFFFFFu; pb3[i][r] = 0xFFFFFFFFu;
        }

    #pragma unroll 1
    for (int jh = 0; jh < 2; ++jh) {
        f32x4 acc[4][4];
        #pragma unroll
        for (int i = 0; i < 4; i++)
            #pragma unroll
            for (int j = 0; j < 4; j++) acc[i][j] = (f32x4){0.f, 0.f, 0.f, 0.f};
        for (int s = 0; s < 8; ++s) {
            f16x8 a[4];
            #pragma unroll
            for (int i = 0; i < 4; ++i) {
                int m = i * 16 + (l & 15);
                int g = s * 4 + (l >> 4);
                int gp = g ^ (m & 7);
                a[i] = *reinterpret_cast<const f16x8*>(&sm.xe[m * ND + gp * 8]);
            }
            #pragma unroll
            for (int j = 0; j < 4; ++j) {
                int f = (wv * 8 + jh * 4 + j) * 8 + s;
                f16x8 bh = *reinterpret_cast<const f16x8*>(&vqh[(size_t)f * 512 + l * 8]);
                #pragma unroll
                for (int i = 0; i < 4; ++i)
                    acc[i][j] = __builtin_amdgcn_mfma_f32_16x16x32_f16(a[i], bh, acc[i][j], 0, 0, 0);
            }
        }
        #pragma unroll
        for (int j = 0; j < 4; ++j) {
            int n = (wv * 8 + jh * 4 + j) * 16 + (l & 15);
            float h = fmaf(0.5f, c2g[n], -SSHIFT);
            #pragma unroll
            for (int i = 0; i < 4; ++i)
                #pragma unroll
                for (int r = 0; r < 4; ++r)
                    insert3(pack_score(h - acc[i][j][r], n),
                            pb1[i][r], pb2[i][r], pb3[i][r]);
        }
    }

    // butterfly merge over the 16-lane code dimension
    #pragma unroll
    for (int i = 0; i < 4; ++i) {
        #pragma unroll
        for (int r = 0; r < 4; ++r) {
            unsigned a1 = pb1[i][r], a2 = pb2[i][r], a3 = pb3[i][r];
            for (int off = 1; off < 16; off <<= 1) {
                unsigned o1 = __shfl_xor((int)a1, off, 64);
                unsigned o2 = __shfl_xor((int)a2, off, 64);
                unsigned o3 = __shfl_xor((int)a3, off, 64);
                unsigned mx = max(a1, o1), mn2 = min(a2, o2);
                unsigned m1 = min(a1, o1);
                unsigned m2 = min(mx, mn2);
                unsigned m3 = min(max(mx, mn2), min(a3, o3));
                a1 = m1; a2 = m2; a3 = m3;
            }
            if ((l & 15) == 0) {
                int m = i * 16 + ((l >> 4) << 2) + r;
                sm.ms1[wv * 64 + m] = a1;
                sm.ms2[wv * 64 + m] = a2;
                sm.ms3[wv * 64 + m] = a3;
            }
        }
    }
    __syncthreads();

    // cross-wave merge (waves cover disjoint code ranges)
    if (t < 64) {
        unsigned b1 = 0xFFFFFFFFu, b2 = 0xFFFFFFFFu, b3 = 0xFFFFFFFFu;
        #pragma unroll
        for (int w = 0; w < 4; ++w) {
            insert3(sm.ms1[w * 64 + t], b1, b2, b3);
            insert3(sm.ms2[w * 64 + t], b1, b2, b3);
            insert3(sm.ms3[w * 64 + t], b1, b2, b3);
        }
        sm.bestidx[t] = (int)(b1 & 511u);
        float s1f = unpack_score(b1), s2f = unpack_score(b2);
        if (s2f - s1f < REFINE_EPS) {
            int slot = atomicAdd(&sm.refine_count, 1);
            if (slot < MAX_REFINE) {
                sm.refine_pos[slot] = t;
                sm.refine_c[slot][0] = (int)(b1 & 511u);
                sm.refine_c[slot][1] = (int)(b2 & 511u);
                sm.refine_c[slot][2] = (int)(b3 & 511u);
            }
        }
        float s1 = s1f;
        #pragma unroll
        for (int off = 32; off; off >>= 1) s1 += __shfl_xor(s1, off, 64);
        if (t == 0) sm.s1tot = s1;
    }
    __syncthreads();

    // --------- rare double-precision refinement (3 candidates) --------------
    {
        int nref = sm.refine_count;
        if (nref > MAX_REFINE) nref = MAX_REFINE;
        for (int rr = 0; rr < nref; rr++) {
            const int pos = sm.refine_pos[rr];
            const int d = t;
            const int py = pos >> 5, px = pos & 31;
            const int r0 = py * 2, c0 = px * 2;
            double s00, s01, s10, s11;
            s00 = s01 = s10 = s11 = (double)conv_bp[d];
            for (int c = 0; c < 3; c++) {
                for (int r = 0; r < 4; r++) {
                    const float* hrow = &sm.halo[c * (HR * HC) + (r0 + r) * HC + c0];
                    double v0 = (double)hrow[0];
                    double v1 = (double)hrow[1];
                    double v2 = (double)hrow[2];
                    double v3 = (double)hrow[3];
                    if (r <= 2) {
                        double w0 = (double)conv_w[d*27 + c*9 + r*3 + 0];
                        double w1 = (double)conv_w[d*27 + c*9 + r*3 + 1];
                        double w2 = (double)conv_w[d*27 + c*9 + r*3 + 2];
                        s00 = fma(w0, v0, s00); s00 = fma(w1, v1, s00); s00 = fma(w2, v2, s00);
                        s01 = fma(w0, v1, s01); s01 = fma(w1, v2, s01); s01 = fma(w2, v3, s01);
                    }
                    if (r >= 1) {
                        double w0 = (double)conv_w[d*27 + c*9 + (r-1)*3 + 0];
                        double w1 = (double)conv_w[d*27 + c*9 + (r-1)*3 + 1];
                        double w2 = (double)conv_w[d*27 + c*9 + (r-1)*3 + 2];
                        s10 = fma(w0, v0, s10); s10 = fma(w1, v1, s10); s10 = fma(w2, v2, s10);
                        s11 = fma(w0, v1, s11); s11 = fma(w1, v2, s11); s11 = fma(w2, v3, s11);
                    }
                }
            }
            double m = fmax(fmax(s00, s01), fmax(s10, s11));
            double bn = (m - (double)mean[d]) * ((double)gamma[d] /
                        sqrt((double)var[d] + 1e-5)) + (double)beta[d];
            double xd = 0.5 * bn * (1.0 + erf(bn * 0.70710678118654752440));
            double p[3], q[3];
            #pragma unroll
            for (int k = 0; k < 3; k++) {
                double cv = (double)cb[(size_t)sm.refine_c[rr][k] * ND + d];
                p[k] = xd * cv;
                q[k] = cv * cv;
            }
            #pragma unroll
            for (int k = 0; k < 3; k++) {
                for (int off = 32; off; off >>= 1) {
                    p[k] += __shfl_xor(p[k], off, 64);
                    q[k] += __shfl_xor(q[k], off, 64);
                }
            }
            if ((t & 63) == 0) {
                #pragma unroll
                for (int k = 0; k < 3; k++) {
                    sm.red[wv * 8 + k * 2 + 0] = p[k];
                    sm.red[wv * 8 + k * 2 + 1] = q[k];
                }
            }
            __syncthreads();
            if (t == 0) {
                double bsc = 1e300; int bidx = 0x7fffffff;
                #pragma unroll
                for (int k = 0; k < 3; k++) {
                    double dot = sm.red[k*2] + sm.red[8 + k*2] + sm.red[16 + k*2] + sm.red[24 + k*2];
                    double cs  = sm.red[k*2+1] + sm.red[8 + k*2+1] + sm.red[16 + k*2+1] + sm.red[24 + k*2+1];
                    double sc = 0.5 * cs - dot;
                    int ci = sm.refine_c[rr][k];
                    if (sc < bsc || (sc == bsc && ci < bidx)) { bsc = sc; bidx = ci; }
                }
                sm.bestidx[pos] = bidx;
            }
            __syncthreads();
        }
    }
    __syncthreads();

    // --------------- write indices, quant (NCHW, 128B runs), loss -----------
    if (t < 64) {
        const int hw = (ty0 + (t >> 5)) * WP + tx0 + (t & 31);
        out[QOUT + (size_t)b * NPOS + hw] = (float)sm.bestidx[t];
    }
    {
        const int code = sm.bestidx[l];
        const int hw = (ty0 + (l >> 5)) * WP + tx0 + (l & 31);
        const float* crow = cb + (size_t)code * ND + wv * 64;
        float* qb = out + (size_t)b * ND * NPOS + hw;
        #pragma unroll
        for (int k4 = 0; k4 < 16; ++k4) {
            float4 cv = *reinterpret_cast<const float4*>(&crow[k4 * 4]);
            const size_t d0 = (size_t)(wv * 64 + k4 * 4);
            qb[(d0 + 0) * NPOS] = cv.x;
            qb[(d0 + 1) * NPOS] = cv.y;
            qb[(d0 + 2) * NPOS] = cv.z;
            qb[(d0 + 3) * NPOS] = cv.w;
        }
    }
    if (t == 0) {
        // per-position dist = |x|^2 + 2*(s' + 128); 64 positions per block
        float tot = sm.sqbuf[0] + sm.sqbuf[1] + sm.sqbuf[2] + sm.sqbuf[3]
                  + 2.0f * sm.s1tot + 2.0f * 64.0f * SSHIFT;
        atomicAdd(out + LOSS_OFF, tot * (1.0f / 67108864.0f));
    }
}

extern "C" void kernel_launch(void* const* d_in, const int* in_sizes, int n_in,
                              void* d_out, int out_size, void* d_ws, size_t ws_size,
                              hipStream_t stream) {
    const float* x      = (const float*)d_in[0];
    const float* conv_w = (const float*)d_in[1];
    const float* conv_b = (const float*)d_in[2];
    const float* gammap = (const float*)d_in[3];
    const float* betap  = (const float*)d_in[4];
    const float* meanp  = (const float*)d_in[5];
    const float* varp   = (const float*)d_in[6];
    const float* cb     = (const float*)d_in[7];
    float* out = (float*)d_out;

    char* wsb = (char*)d_ws;
    float*    c2w  = (float*)wsb;
    _Float16* vqh  = (_Float16*)(wsb + WS_VQH_B);
    _Float16* cwh  = (_Float16*)(wsb + WS_CWH_B);
    float*    scp  = (float*)(wsb + WS_SC_B);
    float*    shp  = (float*)(wsb + WS_SH_B);

    prep_kernel<<<66, 256, 0, stream>>>(cb, conv_w, conv_b, gammap, betap,
                                        meanp, varp, c2w, vqh, cwh, scp, shp,
                                        out + LOSS_OFF);
    vqvae_kernel<<<NB * 256, 256, 0, stream>>>(x, conv_w, cb, c2w, conv_b,
                                               gammap, betap, meanp, varp,
                                               vqh, cwh, scp, shp, out);
}

// Round 5
// 482.721 us; speedup vs baseline: 6.6031x; 1.4045x over previous
//
#include <hip/hip_runtime.h>
#include <math.h>

#define CIN 3
#define HIN 256
#define WIN 256
#define ND 256
#define NK 512
#define HP 128
#define WP 128
#define NPOS (HP*WP)
#define NB 16
#define QOUT ((size_t)NB*(size_t)ND*(size_t)NPOS)      // 67108864
#define IDXOUT ((size_t)NB*(size_t)NPOS)               // 262144
#define LOSS_OFF (QOUT + IDXOUT)
#define REFINE_EPS 0.09f
#define MAX_REFINE 16
#define BN_EPSF 1e-5f
#define SSHIFT 256.0f

// tile: 2 pooled rows x 32 pooled cols = 64 positions per block
#define HR 6
#define HC 66
#define HCH 70                 // padded stride for fp16 halo
#define HALO_N (CIN*HR*HC)     // 1188

typedef _Float16 f16x8 __attribute__((ext_vector_type(8)));
typedef float    f32x4 __attribute__((ext_vector_type(4)));

// ws byte layout: c2s f32[512] @0 ; vqh f16[256*512] @2048 ; cwh f16[16*512]
// @264192 ; scale f32[256] @280576 ; shift f32[256] @281600
#define WS_VQH_B 2048
#define WS_CWH_B 264192
#define WS_SC_B  280576
#define WS_SH_B  281600

struct SMem {
    alignas(16) unsigned short xe[64 * ND];    // fp16 bits, swizzled, 32 KiB
    float halo[HALO_N];                        // fp32 halo (refine), 4.6 KiB
    _Float16 halo_h[CIN * HR * HCH];           // fp16 halo (conv A), 2.5 KiB
    unsigned int ms1[4 * 64];                  // packed top-3 per wave
    unsigned int ms2[4 * 64];
    unsigned int ms3[4 * 64];
    int   bestidx[64];
    int   refine_pos[MAX_REFINE];
    int   refine_c[MAX_REFINE][3];
    int   refine_count;
    float sqbuf[4];
    float s1tot;
    double red[32];
};

// scores are guaranteed positive -> positive-float bits are order-isomorphic
__device__ __forceinline__ unsigned pack_pos(float s, int n) {
    return (__builtin_bit_cast(unsigned, s) & 0xFFFFFE00u) | (unsigned)n;
}
__device__ __forceinline__ float unpack_pos(unsigned u) {
    return __builtin_bit_cast(float, u & 0xFFFFFE00u);
}
__device__ __forceinline__ void insert3(unsigned u, unsigned& b1,
                                        unsigned& b2, unsigned& b3) {
    unsigned t1 = min(u, b1), h1 = max(u, b1);
    b1 = t1;
    unsigned t2 = min(h1, b2), h2 = max(h1, b2);
    b2 = t2;
    b3 = min(h2, b3);
}

__global__ void prep_kernel(const float* __restrict__ cb,
                            const float* __restrict__ conv_w,
                            const float* __restrict__ conv_b,
                            const float* __restrict__ gamma,
                            const float* __restrict__ beta,
                            const float* __restrict__ mean,
                            const float* __restrict__ var,
                            float* __restrict__ c2s,
                            _Float16* __restrict__ vqh,
                            _Float16* __restrict__ cwh,
                            float* __restrict__ scale,
                            float* __restrict__ shift,
                            float* __restrict__ loss_out) {
    const int blk = blockIdx.x;
    const int t = threadIdx.x;
    if (blk < 64) {
        // VQ code fragments (fp16), usable as MFMA A-operand with rows=codes:
        // frag fr = nt*8 + s; lane l: code n = nt*16+(l&15), d = s*32+(l>>4)*8+e
        const int fr = blk * 4 + (t >> 6);
        const int lane = t & 63;
        const int nt = fr >> 3, s = fr & 7;
        const int n = nt * 16 + (lane & 15);
        const int dbase = s * 32 + ((lane >> 4) << 3);
        const float* src = cb + (size_t)n * ND + dbase;
        f16x8 vh;
        #pragma unroll
        for (int e = 0; e < 8; e++) vh[e] = (_Float16)src[e];
        *reinterpret_cast<f16x8*>(&vqh[(size_t)fr * 512 + lane * 8]) = vh;
    } else if (blk == 64) {
        for (int c = t; c < NK; c += 256) {
            const float4* row = reinterpret_cast<const float4*>(cb + (size_t)c * ND);
            float s = 0.f;
            #pragma unroll 8
            for (int i = 0; i < ND / 4; i++) {
                float4 v = row[i];
                s = fmaf(v.x, v.x, s); s = fmaf(v.y, v.y, s);
                s = fmaf(v.z, v.z, s); s = fmaf(v.w, v.w, s);
            }
            c2s[c] = 0.5f * s + SSHIFT;
        }
        {
            int ch = t;
            float inv = gamma[ch] / sqrtf(var[ch] + BN_EPSF);
            scale[ch] = inv;
            shift[ch] = (conv_b[ch] - mean[ch]) * inv + beta[ch];
        }
        if (t == 0) *loss_out = 0.f;
    } else {
        // conv-weight fragments (fp16): 16 N-tiles, K=32 (27 real + 5 zero)
        const int lane = t & 63;
        for (int fr = t >> 6; fr < 16; fr += 4) {
            const int n = fr * 16 + (lane & 15);
            f16x8 vh;
            #pragma unroll
            for (int e = 0; e < 8; e++) {
                int k = ((lane >> 4) << 3) + e;
                vh[e] = (k < 27) ? (_Float16)conv_w[n * 27 + k] : (_Float16)0.f;
            }
            *reinterpret_cast<f16x8*>(&cwh[(size_t)fr * 512 + lane * 8]) = vh;
        }
    }
}

__global__ __launch_bounds__(256, 2)
void vqvae_kernel(const float* __restrict__ x, const float* __restrict__ conv_w,
                  const float* __restrict__ cb, const float* __restrict__ c2s,
                  const float* __restrict__ conv_bp,
                  const float* __restrict__ gamma, const float* __restrict__ beta,
                  const float* __restrict__ mean, const float* __restrict__ var,
                  const _Float16* __restrict__ vqh,
                  const _Float16* __restrict__ cwh,
                  const float* __restrict__ scale,
                  const float* __restrict__ shift,
                  float* __restrict__ out) {
    __shared__ SMem sm;
    const int t = threadIdx.x;
    const int l = t & 63;
    const int wv = t >> 6;
    const int blk = blockIdx.x;
    const int b = blk >> 8;
    const int tile = blk & 255;
    const int ty0 = (tile >> 2) * 2;        // pooled-row origin
    const int tx0 = (tile & 3) * 32;        // pooled-col origin

    // -------------- stage input halo fp32 + fp16 (zero-padded) --------------
    {
        const int iy0 = ty0 * 2 - 1;
        const int ix0 = tx0 * 2 - 1;
        for (int e = t; e < HALO_N; e += 256) {
            int c = e / (HR * HC);
            int rem = e - c * (HR * HC);
            int r = rem / HC;
            int cc = rem - r * HC;
            int iy = iy0 + r, ix = ix0 + cc;
            float v = 0.f;
            if (iy >= 0 && iy < HIN && ix >= 0 && ix < WIN)
                v = x[(((size_t)b * CIN + c) * HIN + iy) * WIN + ix];
            sm.halo[e] = v;
            sm.halo_h[c * (HR * HCH) + r * HCH + cc] = (_Float16)v;
        }
        if (t == 0) sm.refine_count = 0;
    }

    // per-lane k -> fp16-halo offset (k = (l>>4)*8 + e)
    int hoff2[8];
    #pragma unroll
    for (int e = 0; e < 8; e++) {
        int k = ((l >> 4) << 3) + e;
        int c = k / 9;
        int r9 = k - c * 9;
        int dy = r9 / 3;
        int dx = r9 - dy * 3;
        hoff2[e] = (k < 27) ? (c * (HR * HCH) + dy * HCH + dx) : 0;
    }

    // folded BN params for this wave's 64 channels (4 N-tiles)
    float sc4[4], sh4[4];
    #pragma unroll
    for (int j = 0; j < 4; j++) {
        int ch = wv * 64 + j * 16 + (l & 15);
        sc4[j] = scale[ch];
        sh4[j] = shift[ch];
    }
    __syncthreads();

    // ------- conv3x3 via im2col fp16 MFMA + maxpool + BN + exact GELU -------
    float sq = 0.f;
    #pragma unroll 1
    for (int mc = 0; mc < 4; mc++) {
        f16x8 ah[4];
        #pragma unroll
        for (int i = 0; i < 4; i++) {
            const int m16 = l & 15;
            const int p = i * 4 + (m16 >> 2);
            const int q = m16 & 3;
            const int pos = mc * 16 + p;
            const int py = pos >> 5, px = pos & 31;
            const int cy = py * 2 + (q >> 1), cx = px * 2 + (q & 1);
            const int base = cy * HCH + cx;
            #pragma unroll
            for (int e = 0; e < 8; e++)
                ah[i][e] = sm.halo_h[base + hoff2[e]];  // k>=27: junk x zero-w
        }
        #pragma unroll 1
        for (int jh = 0; jh < 2; jh++) {
            f16x8 bw0 = *reinterpret_cast<const f16x8*>(
                &cwh[(wv * 4 + jh * 2 + 0) * 512 + l * 8]);
            f16x8 bw1 = *reinterpret_cast<const f16x8*>(
                &cwh[(wv * 4 + jh * 2 + 1) * 512 + l * 8]);
            f32x4 acc[4][2];
            #pragma unroll
            for (int i = 0; i < 4; i++) {
                acc[i][0] = (f32x4){0.f, 0.f, 0.f, 0.f};
                acc[i][1] = (f32x4){0.f, 0.f, 0.f, 0.f};
            }
            #pragma unroll
            for (int i = 0; i < 4; i++) {
                acc[i][0] = __builtin_amdgcn_mfma_f32_16x16x32_f16(ah[i], bw0, acc[i][0], 0, 0, 0);
                acc[i][1] = __builtin_amdgcn_mfma_f32_16x16x32_f16(ah[i], bw1, acc[i][1], 0, 0, 0);
            }
            #pragma unroll
            for (int i = 0; i < 4; i++) {
                const int pos = mc * 16 + i * 4 + (l >> 4);
                #pragma unroll
                for (int jj = 0; jj < 2; jj++) {
                    const int j = jh * 2 + jj;
                    f32x4 a4 = acc[i][jj];
                    float m = fmaxf(fmaxf(a4[0], a4[1]), fmaxf(a4[2], a4[3]));
                    float bn = fmaf(m, sc4[j], sh4[j]);
                    float g = 0.5f * bn * (1.0f + erff(bn * 0.7071067811865475f));
                    sq = fmaf(g, g, sq);
                    _Float16 h = (_Float16)g;
                    int ch = wv * 64 + j * 16 + (l & 15);
                    int slot = pos * ND + (((ch >> 3) ^ (pos & 7)) << 3) + (ch & 7);
                    sm.xe[slot] = __builtin_bit_cast(unsigned short, h);
                }
            }
        }
    }
    #pragma unroll
    for (int off = 32; off; off >>= 1) sq += __shfl_xor(sq, off, 64);
    if (l == 0) sm.sqbuf[wv] = sq;
    __syncthreads();

    // ----- VQ screening: operand-swapped fp16 MFMA (A=codes, B=x tile) ------
    // wave wv owns codes [wv*128, +128) = 8 code-tiles; C: col=position,
    // row=code-sub -> per-position top-3 state is only pb[4 pos-tiles] x 3.
    unsigned pb1[4], pb2[4], pb3[4];
    #pragma unroll
    for (int j = 0; j < 4; j++) {
        pb1[j] = 0xFFFFFFFFu; pb2[j] = 0xFFFFFFFFu; pb3[j] = 0xFFFFFFFFu;
    }

    #pragma unroll 1
    for (int cg = 0; cg < 4; ++cg) {          // pairs of code tiles
        f32x4 acc[2][4];
        #pragma unroll
        for (int tt = 0; tt < 2; tt++)
            #pragma unroll
            for (int j = 0; j < 4; j++) acc[tt][j] = (f32x4){0.f, 0.f, 0.f, 0.f};

        #pragma unroll 2
        for (int s = 0; s < 8; ++s) {
            f16x8 bx[4];
            #pragma unroll
            for (int j = 0; j < 4; ++j) {
                int n = j * 16 + (l & 15);        // position
                int g = s * 4 + (l >> 4);
                int gp = g ^ (n & 7);
                bx[j] = *reinterpret_cast<const f16x8*>(&sm.xe[n * ND + gp * 8]);
            }
            #pragma unroll
            for (int tt = 0; tt < 2; ++tt) {
                int ct = wv * 8 + cg * 2 + tt;
                f16x8 ac = *reinterpret_cast<const f16x8*>(
                    &vqh[(size_t)(ct * 8 + s) * 512 + l * 8]);
                #pragma unroll
                for (int j = 0; j < 4; ++j)
                    acc[tt][j] = __builtin_amdgcn_mfma_f32_16x16x32_f16(ac, bx[j], acc[tt][j], 0, 0, 0);
            }
        }
        #pragma unroll
        for (int tt = 0; tt < 2; ++tt) {
            int cbase = (wv * 8 + cg * 2 + tt) * 16 + ((l >> 4) << 2);
            float4 c2q = *reinterpret_cast<const float4*>(&c2s[cbase]);
            #pragma unroll
            for (int j = 0; j < 4; ++j) {
                insert3(pack_pos(c2q.x - acc[tt][j][0], cbase + 0), pb1[j], pb2[j], pb3[j]);
                insert3(pack_pos(c2q.y - acc[tt][j][1], cbase + 1), pb1[j], pb2[j], pb3[j]);
                insert3(pack_pos(c2q.z - acc[tt][j][2], cbase + 2), pb1[j], pb2[j], pb3[j]);
                insert3(pack_pos(c2q.w - acc[tt][j][3], cbase + 3), pb1[j], pb2[j], pb3[j]);
            }
        }
    }

    // merge across the 4 lanes sharing a position column (xor 16, 32)
    #pragma unroll
    for (int j = 0; j < 4; ++j) {
        unsigned a1 = pb1[j], a2 = pb2[j], a3 = pb3[j];
        #pragma unroll
        for (int off = 16; off <= 32; off <<= 1) {
            unsigned o1 = __shfl_xor((int)a1, off, 64);
            unsigned o2 = __shfl_xor((int)a2, off, 64);
            unsigned o3 = __shfl_xor((int)a3, off, 64);
            insert3(o1, a1, a2, a3);
            insert3(o2, a1, a2, a3);
            insert3(o3, a1, a2, a3);
        }
        if (l < 16) {
            sm.ms1[wv * 64 + j * 16 + l] = a1;
            sm.ms2[wv * 64 + j * 16 + l] = a2;
            sm.ms3[wv * 64 + j * 16 + l] = a3;
        }
    }
    __syncthreads();

    // cross-wave merge (waves cover disjoint code ranges)
    if (t < 64) {
        unsigned b1 = 0xFFFFFFFFu, b2 = 0xFFFFFFFFu, b3 = 0xFFFFFFFFu;
        #pragma unroll
        for (int w = 0; w < 4; ++w) {
            insert3(sm.ms1[w * 64 + t], b1, b2, b3);
            insert3(sm.ms2[w * 64 + t], b1, b2, b3);
            insert3(sm.ms3[w * 64 + t], b1, b2, b3);
        }
        sm.bestidx[t] = (int)(b1 & 511u);
        float s1f = unpack_pos(b1), s2f = unpack_pos(b2);
        if (s2f - s1f < REFINE_EPS) {
            int slot = atomicAdd(&sm.refine_count, 1);
            if (slot < MAX_REFINE) {
                sm.refine_pos[slot] = t;
                sm.refine_c[slot][0] = (int)(b1 & 511u);
                sm.refine_c[slot][1] = (int)(b2 & 511u);
                sm.refine_c[slot][2] = (int)(b3 & 511u);
            }
        }
        float s1 = s1f;
        #pragma unroll
        for (int off = 32; off; off >>= 1) s1 += __shfl_xor(s1, off, 64);
        if (t == 0) sm.s1tot = s1;
    }
    __syncthreads();

    // --------- rare double-precision refinement (3 candidates) --------------
    {
        int nref = sm.refine_count;
        if (nref > MAX_REFINE) nref = MAX_REFINE;
        for (int rr = 0; rr < nref; rr++) {
            const int pos = sm.refine_pos[rr];
            const int d = t;
            const int py = pos >> 5, px = pos & 31;
            const int r0 = py * 2, c0 = px * 2;
            double s00, s01, s10, s11;
            s00 = s01 = s10 = s11 = (double)conv_bp[d];
            for (int c = 0; c < 3; c++) {
                for (int r = 0; r < 4; r++) {
                    const float* hrow = &sm.halo[c * (HR * HC) + (r0 + r) * HC + c0];
                    double v0 = (double)hrow[0];
                    double v1 = (double)hrow[1];
                    double v2 = (double)hrow[2];
                    double v3 = (double)hrow[3];
                    if (r <= 2) {
                        double w0 = (double)conv_w[d*27 + c*9 + r*3 + 0];
                        double w1 = (double)conv_w[d*27 + c*9 + r*3 + 1];
                        double w2 = (double)conv_w[d*27 + c*9 + r*3 + 2];
                        s00 = fma(w0, v0, s00); s00 = fma(w1, v1, s00); s00 = fma(w2, v2, s00);
                        s01 = fma(w0, v1, s01); s01 = fma(w1, v2, s01); s01 = fma(w2, v3, s01);
                    }
                    if (r >= 1) {
                        double w0 = (double)conv_w[d*27 + c*9 + (r-1)*3 + 0];
                        double w1 = (double)conv_w[d*27 + c*9 + (r-1)*3 + 1];
                        double w2 = (double)conv_w[d*27 + c*9 + (r-1)*3 + 2];
                        s10 = fma(w0, v0, s10); s10 = fma(w1, v1, s10); s10 = fma(w2, v2, s10);
                        s11 = fma(w0, v1, s11); s11 = fma(w1, v2, s11); s11 = fma(w2, v3, s11);
                    }
                }
            }
            double m = fmax(fmax(s00, s01), fmax(s10, s11));
            double bn = (m - (double)mean[d]) * ((double)gamma[d] /
                        sqrt((double)var[d] + 1e-5)) + (double)beta[d];
            double xd = 0.5 * bn * (1.0 + erf(bn * 0.70710678118654752440));
            double p[3], q[3];
            #pragma unroll
            for (int k = 0; k < 3; k++) {
                double cv = (double)cb[(size_t)sm.refine_c[rr][k] * ND + d];
                p[k] = xd * cv;
                q[k] = cv * cv;
            }
            #pragma unroll
            for (int k = 0; k < 3; k++) {
                for (int off = 32; off; off >>= 1) {
                    p[k] += __shfl_xor(p[k], off, 64);
                    q[k] += __shfl_xor(q[k], off, 64);
                }
            }
            if ((t & 63) == 0) {
                #pragma unroll
                for (int k = 0; k < 3; k++) {
                    sm.red[wv * 8 + k * 2 + 0] = p[k];
                    sm.red[wv * 8 + k * 2 + 1] = q[k];
                }
            }
            __syncthreads();
            if (t == 0) {
                double bsc = 1e300; int bidx = 0x7fffffff;
                #pragma unroll
                for (int k = 0; k < 3; k++) {
                    double dot = sm.red[k*2] + sm.red[8 + k*2] + sm.red[16 + k*2] + sm.red[24 + k*2];
                    double cs  = sm.red[k*2+1] + sm.red[8 + k*2+1] + sm.red[16 + k*2+1] + sm.red[24 + k*2+1];
                    double sc = 0.5 * cs - dot;
                    int ci = sm.refine_c[rr][k];
                    if (sc < bsc || (sc == bsc && ci < bidx)) { bsc = sc; bidx = ci; }
                }
                sm.bestidx[pos] = bidx;
            }
            __syncthreads();
        }
    }
    __syncthreads();

    // --------------- write indices, quant (NCHW, 128B runs), loss -----------
    if (t < 64) {
        const int hw = (ty0 + (t >> 5)) * WP + tx0 + (t & 31);
        out[QOUT + (size_t)b * NPOS + hw] = (float)sm.bestidx[t];
    }
    {
        const int code = sm.bestidx[l];
        const int hw = (ty0 + (l >> 5)) * WP + tx0 + (l & 31);
        const float* crow = cb + (size_t)code * ND + wv * 64;
        float* qb = out + (size_t)b * ND * NPOS + hw;
        #pragma unroll
        for (int k4 = 0; k4 < 16; ++k4) {
            float4 cv = *reinterpret_cast<const float4*>(&crow[k4 * 4]);
            const size_t d0 = (size_t)(wv * 64 + k4 * 4);
            qb[(d0 + 0) * NPOS] = cv.x;
            qb[(d0 + 1) * NPOS] = cv.y;
            qb[(d0 + 2) * NPOS] = cv.z;
            qb[(d0 + 3) * NPOS] = cv.w;
        }
    }
    if (t == 0) {
        // per-position dist = |x|^2 + 2*(s1 - SSHIFT); 64 positions per block
        float tot = sm.sqbuf[0] + sm.sqbuf[1] + sm.sqbuf[2] + sm.sqbuf[3]
                  + 2.0f * (sm.s1tot - 64.0f * SSHIFT);
        atomicAdd(out + LOSS_OFF, tot * (1.0f / 67108864.0f));
    }
}

extern "C" void kernel_launch(void* const* d_in, const int* in_sizes, int n_in,
                              void* d_out, int out_size, void* d_ws, size_t ws_size,
                              hipStream_t stream) {
    const float* x      = (const float*)d_in[0];
    const float* conv_w = (const float*)d_in[1];
    const float* conv_b = (const float*)d_in[2];
    const float* gammap = (const float*)d_in[3];
    const float* betap  = (const float*)d_in[4];
    const float* meanp  = (const float*)d_in[5];
    const float* varp   = (const float*)d_in[6];
    const float* cb     = (const float*)d_in[7];
    float* out = (float*)d_out;

    char* wsb = (char*)d_ws;
    float*    c2w  = (float*)wsb;
    _Float16* vqh  = (_Float16*)(wsb + WS_VQH_B);
    _Float16* cwh  = (_Float16*)(wsb + WS_CWH_B);
    float*    scp  = (float*)(wsb + WS_SC_B);
    float*    shp  = (float*)(wsb + WS_SH_B);

    prep_kernel<<<66, 256, 0, stream>>>(cb, conv_w, conv_b, gammap, betap,
                                        meanp, varp, c2w, vqh, cwh, scp, shp,
                                        out + LOSS_OFF);
    vqvae_kernel<<<NB * 256, 256, 0, stream>>>(x, conv_w, cb, c2w, conv_b,
                                               gammap, betap, meanp, varp,
                                               vqh, cwh, scp, shp, out);
}

// Round 6
// 466.425 us; speedup vs baseline: 6.8338x; 1.0349x over previous
//
#include <hip/hip_runtime.h>
#include <math.h>

#define CIN 3
#define HIN 256
#define WIN 256
#define ND 256
#define NK 512
#define HP 128
#define WP 128
#define NPOS (HP*WP)
#define NB 16
#define QOUT ((size_t)NB*(size_t)ND*(size_t)NPOS)      // 67108864
#define IDXOUT ((size_t)NB*(size_t)NPOS)               // 262144
#define LOSS_OFF (QOUT + IDXOUT)
#define REFINE_EPS 0.09f
#define MAX_REFINE 16
#define BN_EPSF 1e-5f
#define SSHIFT 256.0f

// tile: 2 pooled rows x 32 pooled cols = 64 positions per block
#define HR 6
#define HC 66
#define HCH 70                 // padded stride for fp16 halo
#define HALO_N (CIN*HR*HC)     // 1188

typedef _Float16 f16x8 __attribute__((ext_vector_type(8)));
typedef float    f32x4 __attribute__((ext_vector_type(4)));

// ws byte layout: c2s f32[512] @0 ; vqh f16[256*512] @2048 (NEGATED codes);
// cwh f16[16*512] @264192 ; scale f32[256] @280576 ; shift f32[256] @281600
#define WS_VQH_B 2048
#define WS_CWH_B 264192
#define WS_SC_B  280576
#define WS_SH_B  281600

struct SMem {
    alignas(16) unsigned short xe[64 * ND];    // fp16 bits, swizzled, 32 KiB
    float halo[HALO_N];                        // fp32 halo (refine), 4.6 KiB
    _Float16 halo_h[CIN * HR * HCH];           // fp16 halo (conv A), 2.5 KiB
    unsigned int ms1[4 * 64];                  // packed top-3 per wave
    unsigned int ms2[4 * 64];
    unsigned int ms3[4 * 64];
    int   bestidx[64];
    int   refine_pos[MAX_REFINE];
    int   refine_c[MAX_REFINE][3];
    int   refine_count;
    float sqbuf[4];
    float s1tot;
    double red[32];
};

// scores are guaranteed positive -> positive-float bits are order-isomorphic
__device__ __forceinline__ unsigned pack_pos(float s, int n) {
    return (__builtin_bit_cast(unsigned, s) & 0xFFFFFE00u) | (unsigned)n;
}
__device__ __forceinline__ float unpack_pos(unsigned u) {
    return __builtin_bit_cast(float, u & 0xFFFFFE00u);
}
__device__ __forceinline__ void insert3(unsigned u, unsigned& b1,
                                        unsigned& b2, unsigned& b3) {
    unsigned t1 = min(u, b1), h1 = max(u, b1);
    b1 = t1;
    unsigned t2 = min(h1, b2), h2 = max(h1, b2);
    b2 = t2;
    b3 = min(h2, b3);
}

// branchless exact-GELU: Abramowitz-Stegun 7.1.26 erf, |err| <= 1.5e-7
__device__ __forceinline__ float gelu_exact(float v) {
    float z = v * 0.7071067811865476f;
    float az = fabsf(z);
    float t = __builtin_amdgcn_rcpf(fmaf(0.3275911f, az, 1.0f));
    float p = fmaf(1.061405429f, t, -1.453152027f);
    p = fmaf(p, t, 1.421413741f);
    p = fmaf(p, t, -0.284496736f);
    p = fmaf(p, t, 0.254829592f);
    p = p * t;
    float e = __expf(-az * az);
    float erf_az = fmaf(-p, e, 1.0f);          // 1 - erfc
    float er = copysignf(erf_az, z);
    return 0.5f * v * (1.0f + er);
}

__global__ void prep_kernel(const float* __restrict__ cb,
                            const float* __restrict__ conv_w,
                            const float* __restrict__ conv_b,
                            const float* __restrict__ gamma,
                            const float* __restrict__ beta,
                            const float* __restrict__ mean,
                            const float* __restrict__ var,
                            float* __restrict__ c2s,
                            _Float16* __restrict__ vqh,
                            _Float16* __restrict__ cwh,
                            float* __restrict__ scale,
                            float* __restrict__ shift,
                            float* __restrict__ loss_out) {
    const int blk = blockIdx.x;
    const int t = threadIdx.x;
    if (blk < 64) {
        // NEGATED VQ code fragments (fp16), MFMA A-operand, rows=codes:
        // frag fr = nt*8 + s; lane l: code n = nt*16+(l&15), d = s*32+(l>>4)*8+e
        const int fr = blk * 4 + (t >> 6);
        const int lane = t & 63;
        const int nt = fr >> 3, s = fr & 7;
        const int n = nt * 16 + (lane & 15);
        const int dbase = s * 32 + ((lane >> 4) << 3);
        const float* src = cb + (size_t)n * ND + dbase;
        f16x8 vh;
        #pragma unroll
        for (int e = 0; e < 8; e++) vh[e] = (_Float16)(-src[e]);
        *reinterpret_cast<f16x8*>(&vqh[(size_t)fr * 512 + lane * 8]) = vh;
    } else if (blk == 64) {
        for (int c = t; c < NK; c += 256) {
            const float4* row = reinterpret_cast<const float4*>(cb + (size_t)c * ND);
            float s = 0.f;
            #pragma unroll 8
            for (int i = 0; i < ND / 4; i++) {
                float4 v = row[i];
                s = fmaf(v.x, v.x, s); s = fmaf(v.y, v.y, s);
                s = fmaf(v.z, v.z, s); s = fmaf(v.w, v.w, s);
            }
            c2s[c] = 0.5f * s + SSHIFT;
        }
        {
            int ch = t;
            float inv = gamma[ch] / sqrtf(var[ch] + BN_EPSF);
            scale[ch] = inv;
            shift[ch] = (conv_b[ch] - mean[ch]) * inv + beta[ch];
        }
        if (t == 0) *loss_out = 0.f;
    } else {
        // conv-weight fragments (fp16): 16 N-tiles, K=32 (27 real + 5 zero)
        const int lane = t & 63;
        for (int fr = t >> 6; fr < 16; fr += 4) {
            const int n = fr * 16 + (lane & 15);
            f16x8 vh;
            #pragma unroll
            for (int e = 0; e < 8; e++) {
                int k = ((lane >> 4) << 3) + e;
                vh[e] = (k < 27) ? (_Float16)conv_w[n * 27 + k] : (_Float16)0.f;
            }
            *reinterpret_cast<f16x8*>(&cwh[(size_t)fr * 512 + lane * 8]) = vh;
        }
    }
}

__global__ __launch_bounds__(256, 3)
void vqvae_kernel(const float* __restrict__ x, const float* __restrict__ conv_w,
                  const float* __restrict__ cb, const float* __restrict__ c2s,
                  const float* __restrict__ conv_bp,
                  const float* __restrict__ gamma, const float* __restrict__ beta,
                  const float* __restrict__ mean, const float* __restrict__ var,
                  const _Float16* __restrict__ vqh,
                  const _Float16* __restrict__ cwh,
                  const float* __restrict__ scale,
                  const float* __restrict__ shift,
                  float* __restrict__ out) {
    __shared__ SMem sm;
    const int t = threadIdx.x;
    const int l = t & 63;
    const int wv = t >> 6;
    const int blk = blockIdx.x;
    const int b = blk >> 8;
    const int tile = blk & 255;
    const int ty0 = (tile >> 2) * 2;        // pooled-row origin
    const int tx0 = (tile & 3) * 32;        // pooled-col origin

    // -------------- stage input halo fp32 + fp16 (zero-padded) --------------
    {
        const int iy0 = ty0 * 2 - 1;
        const int ix0 = tx0 * 2 - 1;
        for (int e = t; e < HALO_N; e += 256) {
            int c = e / (HR * HC);
            int rem = e - c * (HR * HC);
            int r = rem / HC;
            int cc = rem - r * HC;
            int iy = iy0 + r, ix = ix0 + cc;
            float v = 0.f;
            if (iy >= 0 && iy < HIN && ix >= 0 && ix < WIN)
                v = x[(((size_t)b * CIN + c) * HIN + iy) * WIN + ix];
            sm.halo[e] = v;
            sm.halo_h[c * (HR * HCH) + r * HCH + cc] = (_Float16)v;
        }
        if (t == 0) sm.refine_count = 0;
    }

    // per-lane k -> fp16-halo offset (k = (l>>4)*8 + e)
    int hoff2[8];
    #pragma unroll
    for (int e = 0; e < 8; e++) {
        int k = ((l >> 4) << 3) + e;
        int c = k / 9;
        int r9 = k - c * 9;
        int dy = r9 / 3;
        int dx = r9 - dy * 3;
        hoff2[e] = (k < 27) ? (c * (HR * HCH) + dy * HCH + dx) : 0;
    }

    // folded BN params for this wave's 64 channels (4 N-tiles)
    float sc4[4], sh4[4];
    #pragma unroll
    for (int j = 0; j < 4; j++) {
        int ch = wv * 64 + j * 16 + (l & 15);
        sc4[j] = scale[ch];
        sh4[j] = shift[ch];
    }
    __syncthreads();

    // ------- conv3x3 via im2col fp16 MFMA + maxpool + BN + exact GELU -------
    float sq = 0.f;
    #pragma unroll 1
    for (int mc = 0; mc < 4; mc++) {
        f16x8 ah[4];
        #pragma unroll
        for (int i = 0; i < 4; i++) {
            const int m16 = l & 15;
            const int p = i * 4 + (m16 >> 2);
            const int q = m16 & 3;
            const int pos = mc * 16 + p;
            const int py = pos >> 5, px = pos & 31;
            const int cy = py * 2 + (q >> 1), cx = px * 2 + (q & 1);
            const int base = cy * HCH + cx;
            #pragma unroll
            for (int e = 0; e < 8; e++)
                ah[i][e] = sm.halo_h[base + hoff2[e]];  // k>=27: junk x zero-w
        }
        #pragma unroll 1
        for (int jh = 0; jh < 2; jh++) {
            f16x8 bw0 = *reinterpret_cast<const f16x8*>(
                &cwh[(wv * 4 + jh * 2 + 0) * 512 + l * 8]);
            f16x8 bw1 = *reinterpret_cast<const f16x8*>(
                &cwh[(wv * 4 + jh * 2 + 1) * 512 + l * 8]);
            f32x4 acc[4][2];
            #pragma unroll
            for (int i = 0; i < 4; i++) {
                acc[i][0] = (f32x4){0.f, 0.f, 0.f, 0.f};
                acc[i][1] = (f32x4){0.f, 0.f, 0.f, 0.f};
            }
            #pragma unroll
            for (int i = 0; i < 4; i++) {
                acc[i][0] = __builtin_amdgcn_mfma_f32_16x16x32_f16(ah[i], bw0, acc[i][0], 0, 0, 0);
                acc[i][1] = __builtin_amdgcn_mfma_f32_16x16x32_f16(ah[i], bw1, acc[i][1], 0, 0, 0);
            }
            #pragma unroll
            for (int i = 0; i < 4; i++) {
                const int pos = mc * 16 + i * 4 + (l >> 4);
                #pragma unroll
                for (int jj = 0; jj < 2; jj++) {
                    const int j = jh * 2 + jj;
                    f32x4 a4 = acc[i][jj];
                    float m = fmaxf(fmaxf(a4[0], a4[1]), fmaxf(a4[2], a4[3]));
                    float bn = fmaf(m, sc4[j], sh4[j]);
                    float g = gelu_exact(bn);
                    sq = fmaf(g, g, sq);
                    _Float16 h = (_Float16)g;
                    int ch = wv * 64 + j * 16 + (l & 15);
                    int slot = pos * ND + (((ch >> 3) ^ (pos & 7)) << 3) + (ch & 7);
                    sm.xe[slot] = __builtin_bit_cast(unsigned short, h);
                }
            }
        }
    }
    #pragma unroll
    for (int off = 32; off; off >>= 1) sq += __shfl_xor(sq, off, 64);
    if (l == 0) sm.sqbuf[wv] = sq;
    __syncthreads();

    // ----- VQ screening: operand-swapped fp16 MFMA (A=-codes, B=x tile) -----
    // C initialized with 0.5|c|^2+SSHIFT so acc == score after the K loop.
    unsigned pb1[4], pb2[4], pb3[4];
    #pragma unroll
    for (int j = 0; j < 4; j++) {
        pb1[j] = 0xFFFFFFFFu; pb2[j] = 0xFFFFFFFFu; pb3[j] = 0xFFFFFFFFu;
    }

    #pragma unroll 1
    for (int cg = 0; cg < 4; ++cg) {          // pairs of code tiles
        f32x4 acc[2][4];
        #pragma unroll
        for (int tt = 0; tt < 2; tt++) {
            int cbase = (wv * 8 + cg * 2 + tt) * 16 + ((l >> 4) << 2);
            float4 c2q = *reinterpret_cast<const float4*>(&c2s[cbase]);
            f32x4 ci = {c2q.x, c2q.y, c2q.z, c2q.w};
            #pragma unroll
            for (int j = 0; j < 4; j++) acc[tt][j] = ci;
        }

        #pragma unroll 2
        for (int s = 0; s < 8; ++s) {
            f16x8 bx[4];
            #pragma unroll
            for (int j = 0; j < 4; ++j) {
                int n = j * 16 + (l & 15);        // position
                int g = s * 4 + (l >> 4);
                int gp = g ^ (n & 7);
                bx[j] = *reinterpret_cast<const f16x8*>(&sm.xe[n * ND + gp * 8]);
            }
            #pragma unroll
            for (int tt = 0; tt < 2; ++tt) {
                int ct = wv * 8 + cg * 2 + tt;
                f16x8 ac = *reinterpret_cast<const f16x8*>(
                    &vqh[(size_t)(ct * 8 + s) * 512 + l * 8]);
                #pragma unroll
                for (int j = 0; j < 4; ++j)
                    acc[tt][j] = __builtin_amdgcn_mfma_f32_16x16x32_f16(ac, bx[j], acc[tt][j], 0, 0, 0);
            }
        }
        #pragma unroll
        for (int tt = 0; tt < 2; ++tt) {
            int cbase = (wv * 8 + cg * 2 + tt) * 16 + ((l >> 4) << 2);
            #pragma unroll
            for (int j = 0; j < 4; ++j) {
                insert3(pack_pos(acc[tt][j][0], cbase + 0), pb1[j], pb2[j], pb3[j]);
                insert3(pack_pos(acc[tt][j][1], cbase + 1), pb1[j], pb2[j], pb3[j]);
                insert3(pack_pos(acc[tt][j][2], cbase + 2), pb1[j], pb2[j], pb3[j]);
                insert3(pack_pos(acc[tt][j][3], cbase + 3), pb1[j], pb2[j], pb3[j]);
            }
        }
    }

    // merge across the 4 lanes sharing a position column (xor 16, 32)
    #pragma unroll
    for (int j = 0; j < 4; ++j) {
        unsigned a1 = pb1[j], a2 = pb2[j], a3 = pb3[j];
        #pragma unroll
        for (int off = 16; off <= 32; off <<= 1) {
            unsigned o1 = __shfl_xor((int)a1, off, 64);
            unsigned o2 = __shfl_xor((int)a2, off, 64);
            unsigned o3 = __shfl_xor((int)a3, off, 64);
            insert3(o1, a1, a2, a3);
            insert3(o2, a1, a2, a3);
            insert3(o3, a1, a2, a3);
        }
        if (l < 16) {
            sm.ms1[wv * 64 + j * 16 + l] = a1;
            sm.ms2[wv * 64 + j * 16 + l] = a2;
            sm.ms3[wv * 64 + j * 16 + l] = a3;
        }
    }
    __syncthreads();

    // cross-wave merge (waves cover disjoint code ranges)
    if (t < 64) {
        unsigned b1 = 0xFFFFFFFFu, b2 = 0xFFFFFFFFu, b3 = 0xFFFFFFFFu;
        #pragma unroll
        for (int w = 0; w < 4; ++w) {
            insert3(sm.ms1[w * 64 + t], b1, b2, b3);
            insert3(sm.ms2[w * 64 + t], b1, b2, b3);
            insert3(sm.ms3[w * 64 + t], b1, b2, b3);
        }
        sm.bestidx[t] = (int)(b1 & 511u);
        float s1f = unpack_pos(b1), s2f = unpack_pos(b2);
        if (s2f - s1f < REFINE_EPS) {
            int slot = atomicAdd(&sm.refine_count, 1);
            if (slot < MAX_REFINE) {
                sm.refine_pos[slot] = t;
                sm.refine_c[slot][0] = (int)(b1 & 511u);
                sm.refine_c[slot][1] = (int)(b2 & 511u);
                sm.refine_c[slot][2] = (int)(b3 & 511u);
            }
        }
        float s1 = s1f;
        #pragma unroll
        for (int off = 32; off; off >>= 1) s1 += __shfl_xor(s1, off, 64);
        if (t == 0) sm.s1tot = s1;
    }
    __syncthreads();

    // --------- rare double-precision refinement (3 candidates) --------------
    {
        int nref = sm.refine_count;
        if (nref > MAX_REFINE) nref = MAX_REFINE;
        for (int rr = 0; rr < nref; rr++) {
            const int pos = sm.refine_pos[rr];
            const int d = t;
            const int py = pos >> 5, px = pos & 31;
            const int r0 = py * 2, c0 = px * 2;
            double s00, s01, s10, s11;
            s00 = s01 = s10 = s11 = (double)conv_bp[d];
            for (int c = 0; c < 3; c++) {
                for (int r = 0; r < 4; r++) {
                    const float* hrow = &sm.halo[c * (HR * HC) + (r0 + r) * HC + c0];
                    double v0 = (double)hrow[0];
                    double v1 = (double)hrow[1];
                    double v2 = (double)hrow[2];
                    double v3 = (double)hrow[3];
                    if (r <= 2) {
                        double w0 = (double)conv_w[d*27 + c*9 + r*3 + 0];
                        double w1 = (double)conv_w[d*27 + c*9 + r*3 + 1];
                        double w2 = (double)conv_w[d*27 + c*9 + r*3 + 2];
                        s00 = fma(w0, v0, s00); s00 = fma(w1, v1, s00); s00 = fma(w2, v2, s00);
                        s01 = fma(w0, v1, s01); s01 = fma(w1, v2, s01); s01 = fma(w2, v3, s01);
                    }
                    if (r >= 1) {
                        double w0 = (double)conv_w[d*27 + c*9 + (r-1)*3 + 0];
                        double w1 = (double)conv_w[d*27 + c*9 + (r-1)*3 + 1];
                        double w2 = (double)conv_w[d*27 + c*9 + (r-1)*3 + 2];
                        s10 = fma(w0, v0, s10); s10 = fma(w1, v1, s10); s10 = fma(w2, v2, s10);
                        s11 = fma(w0, v1, s11); s11 = fma(w1, v2, s11); s11 = fma(w2, v3, s11);
                    }
                }
            }
            double m = fmax(fmax(s00, s01), fmax(s10, s11));
            double bn = (m - (double)mean[d]) * ((double)gamma[d] /
                        sqrt((double)var[d] + 1e-5)) + (double)beta[d];
            double xd = 0.5 * bn * (1.0 + erf(bn * 0.70710678118654752440));
            double p[3], q[3];
            #pragma unroll
            for (int k = 0; k < 3; k++) {
                double cv = (double)cb[(size_t)sm.refine_c[rr][k] * ND + d];
                p[k] = xd * cv;
                q[k] = cv * cv;
            }
            #pragma unroll
            for (int k = 0; k < 3; k++) {
                for (int off = 32; off; off >>= 1) {
                    p[k] += __shfl_xor(p[k], off, 64);
                    q[k] += __shfl_xor(q[k], off, 64);
                }
            }
            if ((t & 63) == 0) {
                #pragma unroll
                for (int k = 0; k < 3; k++) {
                    sm.red[wv * 8 + k * 2 + 0] = p[k];
                    sm.red[wv * 8 + k * 2 + 1] = q[k];
                }
            }
            __syncthreads();
            if (t == 0) {
                double bsc = 1e300; int bidx = 0x7fffffff;
                #pragma unroll
                for (int k = 0; k < 3; k++) {
                    double dot = sm.red[k*2] + sm.red[8 + k*2] + sm.red[16 + k*2] + sm.red[24 + k*2];
                    double cs  = sm.red[k*2+1] + sm.red[8 + k*2+1] + sm.red[16 + k*2+1] + sm.red[24 + k*2+1];
                    double sc = 0.5 * cs - dot;
                    int ci = sm.refine_c[rr][k];
                    if (sc < bsc || (sc == bsc && ci < bidx)) { bsc = sc; bidx = ci; }
                }
                sm.bestidx[pos] = bidx;
            }
            __syncthreads();
        }
    }
    __syncthreads();

    // --------------- write indices, quant (NCHW, 128B runs), loss -----------
    if (t < 64) {
        const int hw = (ty0 + (t >> 5)) * WP + tx0 + (t & 31);
        out[QOUT + (size_t)b * NPOS + hw] = (float)sm.bestidx[t];
    }
    {
        const int code = sm.bestidx[l];
        const int hw = (ty0 + (l >> 5)) * WP + tx0 + (l & 31);
        const float* crow = cb + (size_t)code * ND + wv * 64;
        float* qb = out + (size_t)b * ND * NPOS + hw;
        #pragma unroll
        for (int k4 = 0; k4 < 16; ++k4) {
            float4 cv = *reinterpret_cast<const float4*>(&crow[k4 * 4]);
            const size_t d0 = (size_t)(wv * 64 + k4 * 4);
            qb[(d0 + 0) * NPOS] = cv.x;
            qb[(d0 + 1) * NPOS] = cv.y;
            qb[(d0 + 2) * NPOS] = cv.z;
            qb[(d0 + 3) * NPOS] = cv.w;
        }
    }
    if (t == 0) {
        // per-position dist = |x|^2 + 2*(s1 - SSHIFT); 64 positions per block
        float tot = sm.sqbuf[0] + sm.sqbuf[1] + sm.sqbuf[2] + sm.sqbuf[3]
                  + 2.0f * (sm.s1tot - 64.0f * SSHIFT);
        atomicAdd(out + LOSS_OFF, tot * (1.0f / 67108864.0f));
    }
}

extern "C" void kernel_launch(void* const* d_in, const int* in_sizes, int n_in,
                              void* d_out, int out_size, void* d_ws, size_t ws_size,
                              hipStream_t stream) {
    const float* x      = (const float*)d_in[0];
    const float* conv_w = (const float*)d_in[1];
    const float* conv_b = (const float*)d_in[2];
    const float* gammap = (const float*)d_in[3];
    const float* betap  = (const float*)d_in[4];
    const float* meanp  = (const float*)d_in[5];
    const float* varp   = (const float*)d_in[6];
    const float* cb     = (const float*)d_in[7];
    float* out = (float*)d_out;

    char* wsb = (char*)d_ws;
    float*    c2w  = (float*)wsb;
    _Float16* vqh  = (_Float16*)(wsb + WS_VQH_B);
    _Float16* cwh  = (_Float16*)(wsb + WS_CWH_B);
    float*    scp  = (float*)(wsb + WS_SC_B);
    float*    shp  = (float*)(wsb + WS_SH_B);

    prep_kernel<<<66, 256, 0, stream>>>(cb, conv_w, conv_b, gammap, betap,
                                        meanp, varp, c2w, vqh, cwh, scp, shp,
                                        out + LOSS_OFF);
    vqvae_kernel<<<NB * 256, 256, 0, stream>>>(x, conv_w, cb, c2w, conv_b,
                                               gammap, betap, meanp, varp,
                                               vqh, cwh, scp, shp, out);
}